// Round 13
// baseline (113.870 us; speedup 1.0000x reference)
//
#include <hip/hip_runtime.h>
#include <hip/hip_bf16.h>
#include <math.h>

#define BB 2
#define NVIEW 6
#define BN 12
#define CIN 64
#define HH 48
#define WW 48
#define PP (HH*WW)        // 2304
#define OC 192
#define HPA 192
#define HIDP 64
#define KHW 16
#define PK 256
#define PADW 54
#define PADA (PADW*PADW)  // 2916
#define NTOT (BN*PP)      // 27648
#define K1 1728           // 27 taps * 64 ic
#define KVPW 50
#define KVPA (KVPW*KVPW)  // 2500

typedef __attribute__((ext_vector_type(8))) short bf16x8;
typedef __attribute__((ext_vector_type(4))) float f32x4;

// ---- workspace layout (float elements) ----
#define OFF_WEFFB 0
#define SZ_WEFFB_FL (OC*K1/2)              // 165888
#define OFF_BEFF (OFF_WEFFB + SZ_WEFFB_FL)
#define SZ_BEFF 256
#define OFF_CW2B (OFF_BEFF + SZ_BEFF)
#define SZ_CW2B_FL (OC*OC/2)               // 18432
#define OFF_WKVB (OFF_CW2B + SZ_CW2B_FL)
#define SZ_WKVB_FL (64*576/2)              // 18432
#define OFF_PADXT (OFF_WKVB + SZ_WKVB_FL)
#define SZ_PADXT_FL (BN*PADA*64/2)         // 1119744
#define OFF_QB16 (OFF_PADXT + SZ_PADXT_FL)
#define SZ_QB16_FL (BN*PP*64/2)            // 884736
#define OFF_KB16 (OFF_QB16 + SZ_QB16_FL)
#define SZ_KB16_FL (BN*PK*64/2)            // 98304
#define OFF_VB16T (OFF_KB16 + SZ_KB16_FL)
#define SZ_VB16T_FL (BN*64*PK/2)           // 98304
#define OFF_KVPAD (OFF_VB16T + SZ_VB16T_FL)
#define SZ_KVPAD_FL (BN*2*KVPA*64/2)       // 1920000
#define OFF_CONVB (OFF_KVPAD + SZ_KVPAD_FL)
#define SZ_CONVB_FL (BN*2*PP*64/2)         // 1769472
#define OFF_W1SW (OFF_CONVB + SZ_CONVB_FL)
#define SZ_WSW_FL 2048                     // 4096 bf16
#define OFF_W2SW (OFF_W1SW + SZ_WSW_FL)
#define OFF_XVB16 (OFF_W2SW + SZ_WSW_FL)
#define SZ_XVB16_FL (BN*PP*64/2)           // 884736 (bf16 [bn][p][d])

__device__ __forceinline__ void load_lds16(const void* g, void* l) {
    __builtin_amdgcn_global_load_lds(
        (const __attribute__((address_space(1))) unsigned int*)g,
        (__attribute__((address_space(3))) unsigned int*)l, 16, 0, 0);
}

__device__ __forceinline__ unsigned short f2bu(float f) {
    __hip_bfloat16 h = __float2bfloat16(f);
    return *(unsigned short*)&h;
}

__device__ __forceinline__ float bu2f(unsigned short h) {
    unsigned int u = ((unsigned int)h) << 16;
    return *(float*)&u;
}

#define WAITV(N) asm volatile("s_waitcnt vmcnt(" #N ")" ::: "memory")
#define WAITL0() asm volatile("s_waitcnt lgkmcnt(0)" ::: "memory")

// K1: fold pa_cw1 (192x576) into 3 effective dilated convs -> bf16 [oc][r*576+tap*64+ic]
__global__ __launch_bounds__(192) void k_fold(const float* __restrict__ cw1,
                       const float* __restrict__ cb1,
                       const float* __restrict__ w1, const float* __restrict__ b1,
                       const float* __restrict__ w2, const float* __restrict__ b2,
                       const float* __restrict__ w3, const float* __restrict__ b3,
                       __hip_bfloat16* __restrict__ weffb, float* __restrict__ beff) {
    __shared__ float cw1s[8][HPA];
    int b = blockIdx.x;
    int r = b / 72;
    int rem = b % 72;
    int og = rem / 3, tz = rem % 3;
    int tid = threadIdx.x;
    int tg = tz*192 + tid;                 // ic*9 + tap, this block's third
    int ic = tg / 9, tap = tg % 9;
    const float* w = (r==0) ? w1 : (r==1) ? w2 : w3;
    #pragma unroll
    for (int j = 0; j < 8; ++j)
        cw1s[j][tid] = cw1[(size_t)(og*8+j)*(HPA*3) + r*HPA + tid];
    __syncthreads();
    float acc[8] = {0,0,0,0,0,0,0,0};
    for (int c = 0; c < HPA; ++c) {
        float wv = w[(size_t)c*(CIN*9) + tg];
        #pragma unroll
        for (int j = 0; j < 8; ++j)
            acc[j] += cw1s[j][c] * wv;
    }
    #pragma unroll
    for (int j = 0; j < 8; ++j)
        weffb[(size_t)(og*8+j)*K1 + r*576 + tap*64 + ic] = __float2bfloat16(acc[j]);
    if (r == 0 && tz == 0 && tid < 8) {
        int o = og*8 + tid;
        float bacc = cb1[o];
        for (int rr = 0; rr < 3; ++rr) {
            const float* bb = (rr==0)?b1:(rr==1)?b2:b3;
            for (int c = 0; c < HPA; ++c)
                bacc += cw1[(size_t)o*(HPA*3) + rr*HPA + c] * bb[c];
        }
        beff[o] = bacc;
    }
}

// K1b: fused weight prep + kvpad halo zero
__global__ void k_wprep(const float* __restrict__ kvw, const float* __restrict__ cw2,
                        const float* __restrict__ w1, const float* __restrict__ w2,
                        __hip_bfloat16* __restrict__ wkvb, __hip_bfloat16* __restrict__ cw2b,
                        __hip_bfloat16* __restrict__ w1sw, __hip_bfloat16* __restrict__ w2sw,
                        __hip_bfloat16* __restrict__ kvpad) {
    int idx = blockIdx.x*256 + threadIdx.x;
    if (idx < 36864) {
        int oc = idx / 576, rest = idx % 576;
        int tap = rest / 64, ic = rest % 64;
        wkvb[idx] = __float2bfloat16(kvw[(oc*64 + ic)*9 + tap]);
    } else if (idx < 73728) {
        int i = idx - 36864;
        cw2b[i] = __float2bfloat16(cw2[i]);
    } else if (idx < 81920) {
        int i = idx - 73728;
        const float* w = (i < 4096) ? w1 : w2;
        __hip_bfloat16* dst = (i < 4096) ? w1sw : w2sw;
        int j = i & 4095;
        int oc = j >> 6, s = (j >> 3) & 7, e = j & 7;
        int k = ((s ^ (oc & 7)) << 3) + e;
        dst[j] = __float2bfloat16(w[oc*64 + k]);
    } else if (idx < 86624) {
        int i = idx - 81920;
        int bn2 = i / 196, h = i % 196;
        int py, px;
        if (h < 50)       { py = 0;        px = h; }
        else if (h < 100) { py = 49;       px = h - 50; }
        else if (h < 148) { py = h - 99;   px = 0; }
        else              { py = h - 147;  px = 49; }
        bf16x8 z = (bf16x8){0,0,0,0,0,0,0,0};
        __hip_bfloat16* dst = kvpad + ((size_t)bn2*KVPA + py*KVPW + px)*64;
        #pragma unroll
        for (int j = 0; j < 8; ++j) *(bf16x8*)(dst + j*8) = z;
    }
}

// K1d: channels-last padded x, bf16: padxT[bn][spos(54x54)][ic(64)]
__global__ void k_padxT(const float* __restrict__ x, __hip_bfloat16* __restrict__ padxT) {
    int idx = blockIdx.x*256 + threadIdx.x;
    if (idx >= BN*PADA) return;
    int spos = idx % PADA; int bn = idx / PADA;
    int sy = spos / PADW, sx = spos % PADW;
    __hip_bfloat16* dst = padxT + (size_t)idx*64;
    if (sy >= 3 && sy < 51 && sx >= 3 && sx < 51) {
        const float* src = x + (size_t)bn*CIN*PP + (sy-3)*WW + (sx-3);
        #pragma unroll 8
        for (int ic = 0; ic < 64; ++ic) dst[ic] = __float2bfloat16(src[ic*PP]);
    } else {
        #pragma unroll 8
        for (int ic = 0; ic < 64; ++ic) dst[ic] = __float2bfloat16(0.f);
    }
}

// K_MFC: fused MultiFieldConv, T3+T4 pipeline: double-buffered, counted vmcnt
// (never drains in main loop), raw barriers. LDS 64KB: A0@0, A1@24576, B0@49152, B1@57344.
__global__ __launch_bounds__(256) void k_mfc(const __hip_bfloat16* __restrict__ wA,
        const __hip_bfloat16* __restrict__ pxT, const __hip_bfloat16* __restrict__ cw2b,
        const float* __restrict__ beff, const float* __restrict__ cb2,
        __hip_bfloat16* __restrict__ xvb16, __hip_bfloat16* __restrict__ qb16,
        __hip_bfloat16* __restrict__ kvpad) {
    __shared__ __align__(16) char smem[65536];
    int tid = threadIdx.x;
    int wid = tid >> 6, lane = tid & 63;
    int bn = blockIdx.x / 36;
    int pb = (blockIdx.x % 36) * 64;
    int sgr = ((lane&7) ^ (lane>>3)) * 8;
    int l7 = lane & 7, lh = lane >> 4, rrow = lane & 15, gcol = lane >> 4;

    size_t gbase[8];
    int dbase[8];
    #pragma unroll
    for (int s2 = 0; s2 < 8; ++s2) {
        int seg = wid*8 + s2;
        if (seg < 24) {
            int row = seg*8 + (lane>>3);
            gbase[s2] = (size_t)row*K1 + sgr;
            dbase[s2] = seg*1024;
        } else {
            int p = pb + (seg-24)*8 + (lane>>3);
            int py = p / WW, px = p % WW;
            gbase[s2] = ((size_t)bn*PADA + (py+3)*PADW + (px+3))*64 + sgr;
            dbase[s2] = 49152 + (seg-24)*1024;
        }
    }

    auto stage1 = [&](int kt, int par) {
        int r_ = kt / 9, tap = kt - r_*9;
        int doff = (r_+1)*((tap/3 - 1)*PADW + (tap%3 - 1));
        int poA = par ? 24576 : 0;
        int poB = par ? 8192 : 0;
        #pragma unroll
        for (int s2 = 0; s2 < 8; ++s2) {
            int seg = wid*8 + s2;
            const __hip_bfloat16* g = (seg < 24) ? wA + gbase[s2] + kt*64
                                                 : pxT + gbase[s2] + (size_t)doff*64;
            load_lds16(g, smem + dbase[s2] + ((seg < 24) ? poA : poB));
        }
    };

    f32x4 acc1[3][4];
    #pragma unroll
    for (int m = 0; m < 3; ++m)
        #pragma unroll
        for (int nf = 0; nf < 4; ++nf) acc1[m][nf] = (f32x4){0.f,0.f,0.f,0.f};

    stage1(0, 0);
    stage1(1, 1);
    for (int kt = 0; kt < 27; ++kt) {
        int par = kt & 1;
        // barrier1: this step's loads (issued 2 iters ago) landed; kt+1's stay in flight
        if (kt < 26) WAITV(8); else WAITV(0);
        __builtin_amdgcn_s_barrier();
        __builtin_amdgcn_sched_barrier(0);
        int aB = par ? 24576 : 0;
        int bB = 49152 + (par ? 8192 : 0);
        bf16x8 a[3][2], b[4][2];
        #pragma unroll
        for (int kk = 0; kk < 2; ++kk) {
            int gof = ((kk*4 + lh) ^ l7) << 4;
            #pragma unroll
            for (int m = 0; m < 3; ++m)
                a[m][kk] = *(const bf16x8*)(smem + aB + (wid*48 + m*16 + rrow)*128 + gof);
            #pragma unroll
            for (int nf = 0; nf < 4; ++nf)
                b[nf][kk] = *(const bf16x8*)(smem + bB + (nf*16 + rrow)*128 + gof);
        }
        #pragma unroll
        for (int kk = 0; kk < 2; ++kk)
            #pragma unroll
            for (int m = 0; m < 3; ++m)
                #pragma unroll
                for (int nf = 0; nf < 4; ++nf)
                    acc1[m][nf] = __builtin_amdgcn_mfma_f32_16x16x32_bf16(
                        a[m][kk], b[nf][kk], acc1[m][nf], 0, 0, 0);
        // barrier2: all waves' LDS reads of buf[par] done (no vmem drain)
        WAITL0();
        __builtin_amdgcn_s_barrier();
        __builtin_amdgcn_sched_barrier(0);
        if (kt + 2 < 27) stage1(kt+2, par);   // refill the just-consumed buffer
    }

    f32x4 acc2[3][4];
    #pragma unroll
    for (int m = 0; m < 3; ++m)
        #pragma unroll
        for (int nf = 0; nf < 4; ++nf) acc2[m][nf] = (f32x4){0.f,0.f,0.f,0.f};

    for (int kt2 = 0; kt2 < 3; ++kt2) {
        if (kt2) __syncthreads();
        #pragma unroll
        for (int s2 = 0; s2 < 6; ++s2) {
            int seg = wid*6 + s2;
            int row = seg*8 + (lane>>3);
            load_lds16(cw2b + (size_t)row*OC + kt2*64 + sgr, smem + seg*1024);
        }
        #pragma unroll
        for (int m = 0; m < 3; ++m) {
            int oc16 = wid*48 + m*16;
            if ((oc16 >> 6) == kt2) {
                int oc0 = oc16 + gcol*4;
                float4 bz = *(const float4*)&beff[oc0];
                int cb = (oc0 - kt2*64)*2;
                #pragma unroll
                for (int nf = 0; nf < 4; ++nf) {
                    int px = nf*16 + rrow;
                    ushort4 hv;
                    hv.x = f2bu(fmaxf(acc1[m][nf][0] + bz.x, 0.f));
                    hv.y = f2bu(fmaxf(acc1[m][nf][1] + bz.y, 0.f));
                    hv.z = f2bu(fmaxf(acc1[m][nf][2] + bz.z, 0.f));
                    hv.w = f2bu(fmaxf(acc1[m][nf][3] + bz.w, 0.f));
                    *(ushort4*)(smem + 49152 + px*136 + cb) = hv;
                }
            }
        }
        __syncthreads();
        #pragma unroll
        for (int kk = 0; kk < 2; ++kk) {
            int gofA = ((kk*4 + lh) ^ l7) << 4;
            int gofB = (kk*4 + lh) << 4;
            bf16x8 a2[3], b2[4];
            #pragma unroll
            for (int m2 = 0; m2 < 3; ++m2)
                a2[m2] = *(const bf16x8*)(smem + (wid*48 + m2*16 + rrow)*128 + gofA);
            #pragma unroll
            for (int nf = 0; nf < 4; ++nf)
                b2[nf] = *(const bf16x8*)(smem + 49152 + (nf*16 + rrow)*136 + gofB);
            #pragma unroll
            for (int m2 = 0; m2 < 3; ++m2)
                #pragma unroll
                for (int nf = 0; nf < 4; ++nf)
                    acc2[m2][nf] = __builtin_amdgcn_mfma_f32_16x16x32_bf16(
                        a2[m2], b2[nf], acc2[m2][nf], 0, 0, 0);
        }
    }

    #pragma unroll
    for (int m2 = 0; m2 < 3; ++m2) {
        int oc16 = wid*48 + m2*16;
        int sec = oc16 >> 6;
        int oc0 = oc16 + gcol*4;
        float4 cz = *(const float4*)&cb2[oc0];
        #pragma unroll
        for (int nf = 0; nf < 4; ++nf) {
            int px = nf*16 + rrow;
            int p = pb + px;
            ushort4 bv;
            bv.x = f2bu(fmaxf(acc2[m2][nf][0] + cz.x, 0.f));
            bv.y = f2bu(fmaxf(acc2[m2][nf][1] + cz.y, 0.f));
            bv.z = f2bu(fmaxf(acc2[m2][nf][2] + cz.z, 0.f));
            bv.w = f2bu(fmaxf(acc2[m2][nf][3] + cz.w, 0.f));
            if (sec == 0) {
                *(ushort4*)&qb16[((size_t)bn*PP + p)*64 + oc0] = bv;
            } else {
                int kv = sec - 1;
                int py = p / WW, pxx = p % WW;
                int d = oc0 - (sec << 6);
                *(ushort4*)&kvpad[((size_t)(bn*2+kv)*KVPA + (py+1)*KVPW + pxx+1)*64 + d] = bv;
                if (kv == 1)
                    *(ushort4*)&xvb16[((size_t)bn*PP + p)*64 + d] = bv;
            }
        }
    }
}

// K4a: MFMA conv3x3 64->64 on kvpad -> convb, T3+T4 pipeline (counted vmcnt)
__global__ __launch_bounds__(256) void k_kvgemm(const __hip_bfloat16* __restrict__ wA,
        const __hip_bfloat16* __restrict__ kvpad, const float* __restrict__ kvb,
        __hip_bfloat16* __restrict__ convb) {
    __shared__ __align__(16) char smem[49152];
    int tid = threadIdx.x;
    int wid = tid >> 6, lane = tid & 63;
    int tileN = blockIdx.x * 128;
    int bn2 = tileN / PP, p0 = tileN % PP;
    int sgr = ((lane&7) ^ (lane>>3)) * 8;

    size_t gbase[6];
    #pragma unroll
    for (int s2 = 0; s2 < 6; ++s2) {
        int seg = wid*6 + s2;
        if (seg < 8) {
            int row = seg*8 + (lane>>3);
            gbase[s2] = (size_t)row*576 + sgr;
        } else {
            int p = p0 + (seg-8)*8 + (lane>>3);
            int py = p / WW, px = p % WW;
            gbase[s2] = ((size_t)bn2*KVPA + (py+1)*KVPW + px+1)*64 + sgr;
        }
    }
    auto stage2 = [&](int kt, int par) {
        int dy = kt/3 - 1, dx = kt%3 - 1;
        int doff = dy*KVPW + dx;
        #pragma unroll
        for (int s2 = 0; s2 < 6; ++s2) {
            int seg = wid*6 + s2;
            const __hip_bfloat16* g = (seg < 8) ? wA + gbase[s2] + kt*64
                                                : kvpad + gbase[s2] + (size_t)doff*64;
            load_lds16(g, smem + par*24576 + seg*1024);
        }
    };
    int wr = wid >> 1, wc = wid & 1;
    int l7 = lane & 7, lh = lane >> 4;
    int arowb[2], browb[4];
    #pragma unroll
    for (int m = 0; m < 2; ++m)
        arowb[m] = (wr*32 + m*16 + (lane&15))*128;
    #pragma unroll
    for (int nf = 0; nf < 4; ++nf)
        browb[nf] = 8192 + (wc*64 + nf*16 + (lane&15))*128;

    f32x4 acc[2][4];
    #pragma unroll
    for (int m = 0; m < 2; ++m)
        #pragma unroll
        for (int nf = 0; nf < 4; ++nf) acc[m][nf] = (f32x4){0.f,0.f,0.f,0.f};

    stage2(0, 0);
    stage2(1, 1);
    for (int kt = 0; kt < 9; ++kt) {
        int par = kt & 1;
        if (kt < 8) WAITV(6); else WAITV(0);
        __builtin_amdgcn_s_barrier();
        __builtin_amdgcn_sched_barrier(0);
        int po = par*24576;
        bf16x8 a[2][2], b[4][2];
        #pragma unroll
        for (int kk = 0; kk < 2; ++kk) {
            int gof = ((kk*4 + lh) ^ l7) << 4;
            #pragma unroll
            for (int m = 0; m < 2; ++m)
                a[m][kk] = *(const bf16x8*)(smem + po + arowb[m] + gof);
            #pragma unroll
            for (int nf = 0; nf < 4; ++nf)
                b[nf][kk] = *(const bf16x8*)(smem + po + browb[nf] + gof);
        }
        #pragma unroll
        for (int kk = 0; kk < 2; ++kk)
            #pragma unroll
            for (int m = 0; m < 2; ++m)
                #pragma unroll
                for (int nf = 0; nf < 4; ++nf)
                    acc[m][nf] = __builtin_amdgcn_mfma_f32_16x16x32_bf16(
                        a[m][kk], b[nf][kk], acc[m][nf], 0, 0, 0);
        WAITL0();
        __builtin_amdgcn_s_barrier();
        __builtin_amdgcn_sched_barrier(0);
        if (kt + 2 < 9) stage2(kt+2, par);
    }
    #pragma unroll
    for (int m = 0; m < 2; ++m) {
        int rbase = wr*32 + m*16 + (lane>>4)*4;
        float4 bz = *(const float4*)&kvb[rbase];
        #pragma unroll
        for (int nf = 0; nf < 4; ++nf) {
            int col = p0 + wc*64 + nf*16 + (lane&15);
            ushort4 cv;
            cv.x = f2bu(fmaxf(acc[m][nf][0] + bz.x, 0.f));
            cv.y = f2bu(fmaxf(acc[m][nf][1] + bz.y, 0.f));
            cv.z = f2bu(fmaxf(acc[m][nf][2] + bz.z, 0.f));
            cv.w = f2bu(fmaxf(acc[m][nf][3] + bz.w, 0.f));
            *(ushort4*)&convb[((size_t)bn2*PP + col)*64 + rbase] = cv;
        }
    }
}

// K4b: 3x3 avgpool on convb -> kbufb bf16 [bn][k][d], vbufT bf16 [bn][d][k]
__global__ __launch_bounds__(256) void k_pool(const __hip_bfloat16* __restrict__ convb,
        __hip_bfloat16* __restrict__ kbufb, __hip_bfloat16* __restrict__ vbufT) {
    int idx = blockIdx.x*256 + threadIdx.x;
    int dg = idx % 8; idx /= 8;
    int pp = idx % PK; idx /= PK;
    int bn2 = idx;
    int kv = bn2 & 1, bn = bn2 >> 1;
    int qy = pp / KHW, qx = pp % KHW;
    float s[8] = {0,0,0,0,0,0,0,0};
    const __hip_bfloat16* base = convb + (size_t)bn2*PP*64 + dg*8;
    #pragma unroll
    for (int sy = 0; sy < 3; ++sy)
        #pragma unroll
        for (int sx = 0; sx < 3; ++sx) {
            union { bf16x8 v; unsigned short h[8]; } c;
            c.v = *(const bf16x8*)(base + ((size_t)(qy*3+sy)*WW + qx*3+sx)*64);
            #pragma unroll
            for (int j = 0; j < 8; ++j) s[j] += bu2f(c.h[j]);
        }
    if (kv == 0) {
        union { ushort4 u[2]; unsigned short h[8]; } cv;
        #pragma unroll
        for (int j = 0; j < 8; ++j) cv.h[j] = f2bu(s[j] * (1.f/9.f));
        ushort4* dst = (ushort4*)(kbufb + ((size_t)bn*PK + pp)*64 + dg*8);
        dst[0] = cv.u[0]; dst[1] = cv.u[1];
    } else {
        #pragma unroll
        for (int j = 0; j < 8; ++j)
            vbufT[((size_t)bn*64 + dg*8 + j)*PK + pp] = __float2bfloat16(s[j]*(1.f/81.f));
    }
}

// K5: fused MFMA leave-one-out sigmoid attention + output MLP.
__global__ __launch_bounds__(256) void k_attn4(const __hip_bfloat16* __restrict__ qb16,
        const __hip_bfloat16* __restrict__ kbufb, const __hip_bfloat16* __restrict__ vbufT,
        const __hip_bfloat16* __restrict__ xvb16, const float* __restrict__ scales,
        const __hip_bfloat16* __restrict__ w1sw, const __hip_bfloat16* __restrict__ w2sw,
        const float* __restrict__ b1, const float* __restrict__ b2,
        float* __restrict__ out) {
    __shared__ __align__(16) char smem[40960];
    char* Qs  = smem;
    char* Ks  = smem + 8192;    // -> Rs
    char* Vs  = smem + 16384;   // -> W1s
    char* Ps  = smem + 24576;   // -> W2s
    char* XVs = smem + 32768;   // -> Ts
    int tid = threadIdx.x;
    int wid = tid >> 6, lane = tid & 63;
    int qt = blockIdx.x % 36;
    int bn = blockIdx.x / 36;
    int b = bn / NVIEW, n = bn % NVIEW;
    int p0 = qt*64;
    float sc = scales[n];

    {
        const char* gq  = (const char*)(qb16  + ((size_t)bn*PP + p0)*64);
        const char* gxv = (const char*)(xvb16 + ((size_t)bn*PP + p0)*64);
        #pragma unroll
        for (int i = 0; i < 2; ++i) {
            int s = wid*2 + i;
            int lin = s*1024 + lane*16;
            int r = lin >> 7, c = (lin >> 4) & 7;
            int gof = (r<<7) + ((c ^ (r&7)) << 4);
            load_lds16(gq + gof, Qs + s*1024);
            load_lds16(gxv + gof, XVs + s*1024);
        }
    }
    int arow = wid*16 + (lane&15);
    int brow = lane&15;
    int gcol = lane>>4;
    int vrow = tid >> 2;
    int vc2 = (tid & 3) * 2;

    f32x4 oacc[4];
    #pragma unroll
    for (int i = 0; i < 4; ++i) oacc[i] = (f32x4){0,0,0,0};

    for (int mi = 0; mi < NVIEW-1; ++mi) {
        int m = mi + (mi >= n ? 1 : 0);
        int bnk = b*NVIEW + m;
        const char* gk = (const char*)(kbufb + (size_t)bnk*PK*64);
        const __hip_bfloat16* gv = vbufT + (size_t)bnk*64*PK;
        for (int kc = 0; kc < 4; ++kc) {
            __syncthreads();
            #pragma unroll
            for (int i = 0; i < 2; ++i) {
                int s = wid*2 + i;
                int lin = s*1024 + lane*16;
                int r = lin >> 7, c = (lin >> 4) & 7;
                int gof = (r<<7) + ((c ^ (r&7)) << 4);
                load_lds16(gk + (size_t)kc*8192 + gof, Ks + s*1024);
            }
            {
                const __hip_bfloat16* src = gv + vrow*PK + kc*64 + vc2*8;
                bf16x8 v0 = *(const bf16x8*)src;
                bf16x8 v1 = *(const bf16x8*)(src+8);
                *(bf16x8*)(Vs + vrow*128 + ((vc2 ^ (vrow&7))<<4)) = v0;
                *(bf16x8*)(Vs + vrow*128 + (((vc2+1) ^ (vrow&7))<<4)) = v1;
            }
            __syncthreads();
            f32x4 sacc[4];
            #pragma unroll
            for (int i = 0; i < 4; ++i) sacc[i] = (f32x4){0,0,0,0};
            #pragma unroll
            for (int kk = 0; kk < 2; ++kk) {
                int g = kk*4 + gcol;
                bf16x8 af = *(const bf16x8*)(Ks + arow*128 + ((g ^ (arow&7))<<4));
                #pragma unroll
                for (int nf = 0; nf < 4; ++nf) {
                    int q = nf*16 + brow;
                    bf16x8 bq = *(const bf16x8*)(Qs + q*128 + ((g ^ (q&7))<<4));
                    sacc[nf] = __builtin_amdgcn_mfma_f32_16x16x32_bf16(af, bq, sacc[nf], 0,0,0);
                }
            }
            {
                int kbase = wid*16 + gcol*4;
                #pragma unroll
                for (int nf = 0; nf < 4; ++nf) {
                    int q = nf*16 + brow;
                    ushort4 pu;
                    float e0 = __expf(-sacc[nf][0]*0.125f);
                    float e1 = __expf(-sacc[nf][1]*0.125f);
                    float e2 = __expf(-sacc[nf][2]*0.125f);
                    float e3 = __expf(-sacc[nf][3]*0.125f);
                    pu.x = f2bu(__builtin_amdgcn_rcpf(1.f+e0));
                    pu.y = f2bu(__builtin_amdgcn_rcpf(1.f+e1));
                    pu.z = f2bu(__builtin_amdgcn_rcpf(1.f+e2));
                    pu.w = f2bu(__builtin_amdgcn_rcpf(1.f+e3));
                    *(ushort4*)(Ps + q*128 + (((kbase>>3) ^ (q&7))<<4) + (kbase&7)*2) = pu;
                }
            }
            __syncthreads();
            #pragma unroll
            for (int kk = 0; kk < 2; ++kk) {
                int g = kk*4 + gcol;
                int qr = wid*16 + brow;
                bf16x8 pf = *(const bf16x8*)(Ps + qr*128 + ((g ^ (qr&7))<<4));
                #pragma unroll
                for (int nf = 0; nf < 4; ++nf) {
                    int d = nf*16 + brow;
                    bf16x8 vf = *(const bf16x8*)(Vs + d*128 + ((g ^ (d&7))<<4));
                    oacc[nf] = __builtin_amdgcn_mfma_f32_16x16x32_bf16(pf, vf, oacc[nf], 0,0,0);
                }
            }
        }
    }

    __syncthreads();
    #pragma unroll
    for (int i = 0; i < 4; ++i) {
        int seg = wid*4 + i;
        const char* src = (seg < 8) ? (const char*)w1sw + seg*1024
                                    : (const char*)w2sw + (seg-8)*1024;
        load_lds16(src + lane*16, ((seg < 8) ? Vs : Ps) + (seg & 7)*1024);
    }
    #pragma unroll
    for (int nf = 0; nf < 4; ++nf) {
        int d = nf*16 + brow;
        #pragma unroll
        for (int r = 0; r < 4; ++r) {
            int q = wid*16 + gcol*4 + r;
            int off = q*128 + (((d>>3) ^ (q&7))<<4) + (d&7)*2;
            float xv = bu2f(*(const unsigned short*)(XVs + off));
            *(unsigned short*)(Ks + off) = f2bu(fmaxf(oacc[nf][r] + sc*xv, 0.f));
        }
    }
    __syncthreads();
    f32x4 acc1[4];
    #pragma unroll
    for (int nf = 0; nf < 4; ++nf) acc1[nf] = (f32x4){0,0,0,0};
    #pragma unroll
    for (int kk = 0; kk < 2; ++kk) {
        int g = kk*4 + gcol;
        int oc = wid*16 + brow;
        bf16x8 af = *(const bf16x8*)(Vs + oc*128 + ((g ^ (oc&7)) << 4));
        #pragma unroll
        for (int nf = 0; nf < 4; ++nf) {
            int px = nf*16 + brow;
            bf16x8 bf = *(const bf16x8*)(Ks + px*128 + ((g ^ (px&7)) << 4));
            acc1[nf] = __builtin_amdgcn_mfma_f32_16x16x32_bf16(af, bf, acc1[nf], 0,0,0);
        }
    }
    {
        int oc0 = wid*16 + gcol*4;
        float4 bz = *(const float4*)&b1[oc0];
        #pragma unroll
        for (int nf = 0; nf < 4; ++nf) {
            int px = nf*16 + brow;
            ushort4 tv;
            tv.x = f2bu(fmaxf(acc1[nf][0] + bz.x, 0.f));
            tv.y = f2bu(fmaxf(acc1[nf][1] + bz.y, 0.f));
            tv.z = f2bu(fmaxf(acc1[nf][2] + bz.z, 0.f));
            tv.w = f2bu(fmaxf(acc1[nf][3] + bz.w, 0.f));
            *(ushort4*)(XVs + px*128 + (((oc0>>3) ^ (px&7)) << 4) + (oc0&7)*2) = tv;
        }
    }
    __syncthreads();
    f32x4 acc2[4];
    #pragma unroll
    for (int nf = 0; nf < 4; ++nf) acc2[nf] = (f32x4){0,0,0,0};
    #pragma unroll
    for (int kk = 0; kk < 2; ++kk) {
        int g = kk*4 + gcol;
        int oc = wid*16 + brow;
        bf16x8 af = *(const bf16x8*)(Ps + oc*128 + ((g ^ (oc&7)) << 4));
        #pragma unroll
        for (int nf = 0; nf < 4; ++nf) {
            int px = nf*16 + brow;
            bf16x8 bf = *(const bf16x8*)(XVs + px*128 + ((g ^ (px&7)) << 4));
            acc2[nf] = __builtin_amdgcn_mfma_f32_16x16x32_bf16(af, bf, acc2[nf], 0,0,0);
        }
    }
    {
        int oc0 = wid*16 + gcol*4;
        float4 bz = *(const float4*)&b2[oc0];
        #pragma unroll
        for (int nf = 0; nf < 4; ++nf) {
            int px = nf*16 + brow;
            float* dst = out + ((size_t)bn*64 + oc0)*PP + p0 + px;
            dst[0*PP] = fmaxf(acc2[nf][0] + bz.x, 0.f);
            dst[1*PP] = fmaxf(acc2[nf][1] + bz.y, 0.f);
            dst[2*PP] = fmaxf(acc2[nf][2] + bz.z, 0.f);
            dst[3*PP] = fmaxf(acc2[nf][3] + bz.w, 0.f);
        }
    }
}

extern "C" void kernel_launch(void* const* d_in, const int* in_sizes, int n_in,
                              void* d_out, int out_size, void* d_ws, size_t ws_size,
                              hipStream_t stream) {
    (void)in_sizes; (void)n_in; (void)out_size; (void)ws_size;
    const float* x      = (const float*)d_in[0];
    const float* pa_w1  = (const float*)d_in[1];
    const float* pa_b1  = (const float*)d_in[2];
    const float* pa_w2  = (const float*)d_in[3];
    const float* pa_b2  = (const float*)d_in[4];
    const float* pa_w3  = (const float*)d_in[5];
    const float* pa_b3  = (const float*)d_in[6];
    const float* pa_cw1 = (const float*)d_in[7];
    const float* pa_cb1 = (const float*)d_in[8];
    const float* pa_cw2 = (const float*)d_in[9];
    const float* pa_cb2 = (const float*)d_in[10];
    const float* kv_w   = (const float*)d_in[11];
    const float* kv_b   = (const float*)d_in[12];
    const float* out_w1 = (const float*)d_in[13];
    const float* out_b1 = (const float*)d_in[14];
    const float* out_w2 = (const float*)d_in[15];
    const float* out_b2 = (const float*)d_in[16];
    const float* scales = (const float*)d_in[17];
    float* out = (float*)d_out;
    float* ws  = (float*)d_ws;

    __hip_bfloat16* weffb = (__hip_bfloat16*)(ws + OFF_WEFFB);
    float* beff = ws + OFF_BEFF;
    __hip_bfloat16* cw2b  = (__hip_bfloat16*)(ws + OFF_CW2B);
    __hip_bfloat16* wkvb  = (__hip_bfloat16*)(ws + OFF_WKVB);
    __hip_bfloat16* padxT = (__hip_bfloat16*)(ws + OFF_PADXT);
    __hip_bfloat16* qb16  = (__hip_bfloat16*)(ws + OFF_QB16);
    __hip_bfloat16* kbufb = (__hip_bfloat16*)(ws + OFF_KB16);
    __hip_bfloat16* vbufT = (__hip_bfloat16*)(ws + OFF_VB16T);
    __hip_bfloat16* kvpad = (__hip_bfloat16*)(ws + OFF_KVPAD);
    __hip_bfloat16* convb = (__hip_bfloat16*)(ws + OFF_CONVB);
    __hip_bfloat16* w1sw  = (__hip_bfloat16*)(ws + OFF_W1SW);
    __hip_bfloat16* w2sw  = (__hip_bfloat16*)(ws + OFF_W2SW);
    __hip_bfloat16* xvb16 = (__hip_bfloat16*)(ws + OFF_XVB16);

    k_fold<<<216, 192, 0, stream>>>(pa_cw1, pa_cb1, pa_w1, pa_b1,
                                    pa_w2, pa_b2, pa_w3, pa_b3, weffb, beff);
    k_wprep<<<339, 256, 0, stream>>>(kv_w, pa_cw2, out_w1, out_w2,
                                     wkvb, cw2b, w1sw, w2sw, kvpad);
    k_padxT<<<(BN*PADA+255)/256, 256, 0, stream>>>(x, padxT);
    k_mfc<<<NTOT/64, 256, 0, stream>>>(weffb, padxT, cw2b, beff, pa_cb2,
                                       xvb16, qb16, kvpad);
    k_kvgemm<<<BN*2*PP/128, 256, 0, stream>>>(wkvb, kvpad, kv_b, convb);
    k_pool<<<BN*2*PK*8/256, 256, 0, stream>>>(convb, kbufb, vbufT);
    k_attn4<<<BN*36, 256, 0, stream>>>(qb16, kbufb, vbufT, xvb16, scales,
                                       w1sw, w2sw, out_b1, out_b2, out);
}

// Round 15
// 111.531 us; speedup vs baseline: 1.0210x; 1.0210x over previous
//
#include <hip/hip_runtime.h>
#include <hip/hip_bf16.h>
#include <math.h>

#define BB 2
#define NVIEW 6
#define BN 12
#define CIN 64
#define HH 48
#define WW 48
#define PP (HH*WW)        // 2304
#define OC 192
#define HPA 192
#define HIDP 64
#define KHW 16
#define PK 256
#define PADW 54
#define PADA (PADW*PADW)  // 2916
#define NTOT (BN*PP)      // 27648
#define K1 1728           // 27 taps * 64 ic
#define KVPW 50
#define KVPA (KVPW*KVPW)  // 2500

typedef __attribute__((ext_vector_type(8))) short bf16x8;
typedef __attribute__((ext_vector_type(4))) float f32x4;

// ---- workspace layout (float elements) ----
#define OFF_WEFFB 0
#define SZ_WEFFB_FL (OC*K1/2)              // 165888
#define OFF_BEFF (OFF_WEFFB + SZ_WEFFB_FL)
#define SZ_BEFF 256
#define OFF_CW2B (OFF_BEFF + SZ_BEFF)
#define SZ_CW2B_FL (OC*OC/2)               // 18432
#define OFF_WKVB (OFF_CW2B + SZ_CW2B_FL)
#define SZ_WKVB_FL (64*576/2)              // 18432
#define OFF_PADXT (OFF_WKVB + SZ_WKVB_FL)
#define SZ_PADXT_FL (BN*PADA*64/2)         // 1119744
#define OFF_QB16 (OFF_PADXT + SZ_PADXT_FL)
#define SZ_QB16_FL (BN*PP*64/2)            // 884736
#define OFF_KB16 (OFF_QB16 + SZ_QB16_FL)
#define SZ_KB16_FL (BN*PK*64/2)            // 98304
#define OFF_VB16T (OFF_KB16 + SZ_KB16_FL)
#define SZ_VB16T_FL (BN*64*PK/2)           // 98304
#define OFF_KVPAD (OFF_VB16T + SZ_VB16T_FL)
#define SZ_KVPAD_FL (BN*2*KVPA*64/2)       // 1920000
#define OFF_CONVB (OFF_KVPAD + SZ_KVPAD_FL)
#define SZ_CONVB_FL (BN*2*PP*64/2)         // 1769472
#define OFF_W1SW (OFF_CONVB + SZ_CONVB_FL)
#define SZ_WSW_FL 2048                     // 4096 bf16
#define OFF_W2SW (OFF_W1SW + SZ_WSW_FL)
#define OFF_XVB16 (OFF_W2SW + SZ_WSW_FL)
#define SZ_XVB16_FL (BN*PP*64/2)           // 884736 (bf16 [bn][p][d])

__device__ __forceinline__ void load_lds16(const void* g, void* l) {
    __builtin_amdgcn_global_load_lds(
        (const __attribute__((address_space(1))) unsigned int*)g,
        (__attribute__((address_space(3))) unsigned int*)l, 16, 0, 0);
}

__device__ __forceinline__ unsigned short f2bu(float f) {
    __hip_bfloat16 h = __float2bfloat16(f);
    return *(unsigned short*)&h;
}

__device__ __forceinline__ float bu2f(unsigned short h) {
    unsigned int u = ((unsigned int)h) << 16;
    return *(float*)&u;
}

// K1: fold pa_cw1 (192x576) into 3 effective dilated convs -> bf16 [oc][r*576+tap*64+ic]
__global__ __launch_bounds__(192) void k_fold(const float* __restrict__ cw1,
                       const float* __restrict__ cb1,
                       const float* __restrict__ w1, const float* __restrict__ b1,
                       const float* __restrict__ w2, const float* __restrict__ b2,
                       const float* __restrict__ w3, const float* __restrict__ b3,
                       __hip_bfloat16* __restrict__ weffb, float* __restrict__ beff) {
    __shared__ float cw1s[8][HPA];
    int b = blockIdx.x;
    int r = b / 72;
    int rem = b % 72;
    int og = rem / 3, tz = rem % 3;
    int tid = threadIdx.x;
    int tg = tz*192 + tid;                 // ic*9 + tap, this block's third
    int ic = tg / 9, tap = tg % 9;
    const float* w = (r==0) ? w1 : (r==1) ? w2 : w3;
    #pragma unroll
    for (int j = 0; j < 8; ++j)
        cw1s[j][tid] = cw1[(size_t)(og*8+j)*(HPA*3) + r*HPA + tid];
    __syncthreads();
    float acc[8] = {0,0,0,0,0,0,0,0};
    for (int c = 0; c < HPA; ++c) {
        float wv = w[(size_t)c*(CIN*9) + tg];
        #pragma unroll
        for (int j = 0; j < 8; ++j)
            acc[j] += cw1s[j][c] * wv;
    }
    #pragma unroll
    for (int j = 0; j < 8; ++j)
        weffb[(size_t)(og*8+j)*K1 + r*576 + tap*64 + ic] = __float2bfloat16(acc[j]);
    if (r == 0 && tz == 0 && tid < 8) {
        int o = og*8 + tid;
        float bacc = cb1[o];
        for (int rr = 0; rr < 3; ++rr) {
            const float* bb = (rr==0)?b1:(rr==1)?b2:b3;
            for (int c = 0; c < HPA; ++c)
                bacc += cw1[(size_t)o*(HPA*3) + rr*HPA + c] * bb[c];
        }
        beff[o] = bacc;
    }
}

// K1b: fused weight prep + kvpad halo zero
__global__ void k_wprep(const float* __restrict__ kvw, const float* __restrict__ cw2,
                        const float* __restrict__ w1, const float* __restrict__ w2,
                        __hip_bfloat16* __restrict__ wkvb, __hip_bfloat16* __restrict__ cw2b,
                        __hip_bfloat16* __restrict__ w1sw, __hip_bfloat16* __restrict__ w2sw,
                        __hip_bfloat16* __restrict__ kvpad) {
    int idx = blockIdx.x*256 + threadIdx.x;
    if (idx < 36864) {
        int oc = idx / 576, rest = idx % 576;
        int tap = rest / 64, ic = rest % 64;
        wkvb[idx] = __float2bfloat16(kvw[(oc*64 + ic)*9 + tap]);
    } else if (idx < 73728) {
        int i = idx - 36864;
        cw2b[i] = __float2bfloat16(cw2[i]);
    } else if (idx < 81920) {
        int i = idx - 73728;
        const float* w = (i < 4096) ? w1 : w2;
        __hip_bfloat16* dst = (i < 4096) ? w1sw : w2sw;
        int j = i & 4095;
        int oc = j >> 6, s = (j >> 3) & 7, e = j & 7;
        int k = ((s ^ (oc & 7)) << 3) + e;
        dst[j] = __float2bfloat16(w[oc*64 + k]);
    } else if (idx < 86624) {
        int i = idx - 81920;
        int bn2 = i / 196, h = i % 196;
        int py, px;
        if (h < 50)       { py = 0;        px = h; }
        else if (h < 100) { py = 49;       px = h - 50; }
        else if (h < 148) { py = h - 99;   px = 0; }
        else              { py = h - 147;  px = 49; }
        bf16x8 z = (bf16x8){0,0,0,0,0,0,0,0};
        __hip_bfloat16* dst = kvpad + ((size_t)bn2*KVPA + py*KVPW + px)*64;
        #pragma unroll
        for (int j = 0; j < 8; ++j) *(bf16x8*)(dst + j*8) = z;
    }
}

// K1d: channels-last padded x, bf16: padxT[bn][spos(54x54)][ic(64)]
__global__ void k_padxT(const float* __restrict__ x, __hip_bfloat16* __restrict__ padxT) {
    int idx = blockIdx.x*256 + threadIdx.x;
    if (idx >= BN*PADA) return;
    int spos = idx % PADA; int bn = idx / PADA;
    int sy = spos / PADW, sx = spos % PADW;
    __hip_bfloat16* dst = padxT + (size_t)idx*64;
    if (sy >= 3 && sy < 51 && sx >= 3 && sx < 51) {
        const float* src = x + (size_t)bn*CIN*PP + (sy-3)*WW + (sx-3);
        #pragma unroll 8
        for (int ic = 0; ic < 64; ++ic) dst[ic] = __float2bfloat16(src[ic*PP]);
    } else {
        #pragma unroll 8
        for (int ic = 0; ic < 64; ++ic) dst[ic] = __float2bfloat16(0.f);
    }
}

// K_MFC: fused MultiFieldConv, T3-minimum pipelined: double-buffered stage issued
// BEFORE current step's compute, ONE barrier per K-step.
// LDS 64KB: A0@0 24K, A1@24576 24K, B0@49152 8K, B1@57344 8K; H @49152 (phase2).
__global__ __launch_bounds__(256) void k_mfc(const __hip_bfloat16* __restrict__ wA,
        const __hip_bfloat16* __restrict__ pxT, const __hip_bfloat16* __restrict__ cw2b,
        const float* __restrict__ beff, const float* __restrict__ cb2,
        __hip_bfloat16* __restrict__ xvb16, __hip_bfloat16* __restrict__ qb16,
        __hip_bfloat16* __restrict__ kvpad) {
    __shared__ __align__(16) char smem[65536];
    int tid = threadIdx.x;
    int wid = tid >> 6, lane = tid & 63;
    int bn = blockIdx.x / 36;
    int pb = (blockIdx.x % 36) * 64;
    int sgr = ((lane&7) ^ (lane>>3)) * 8;     // pre-swizzled source granule
    int l7 = lane & 7, lh = lane >> 4, rrow = lane & 15, gcol = lane >> 4;

    size_t gbase[8];
    int dbase[8];
    #pragma unroll
    for (int s2 = 0; s2 < 8; ++s2) {
        int seg = wid*8 + s2;
        if (seg < 24) {
            int row = seg*8 + (lane>>3);
            gbase[s2] = (size_t)row*K1 + sgr;
            dbase[s2] = seg*1024;
        } else {
            int p = pb + (seg-24)*8 + (lane>>3);
            int py = p / WW, px = p % WW;
            gbase[s2] = ((size_t)bn*PADA + (py+3)*PADW + (px+3))*64 + sgr;
            dbase[s2] = 49152 + (seg-24)*1024;
        }
    }

    auto stage1 = [&](int kt, int par) {
        int r_ = kt / 9, tap = kt - r_*9;
        int doff = (r_+1)*((tap/3 - 1)*PADW + (tap%3 - 1));
        int poA = par ? 24576 : 0;
        int poB = par ? 8192 : 0;
        #pragma unroll
        for (int s2 = 0; s2 < 8; ++s2) {
            int seg = wid*8 + s2;
            const __hip_bfloat16* g = (seg < 24) ? wA + gbase[s2] + kt*64
                                                 : pxT + gbase[s2] + (size_t)doff*64;
            load_lds16(g, smem + dbase[s2] + ((seg < 24) ? poA : poB));
        }
    };

    f32x4 acc1[3][4];
    #pragma unroll
    for (int m = 0; m < 3; ++m)
        #pragma unroll
        for (int nf = 0; nf < 4; ++nf) acc1[m][nf] = (f32x4){0.f,0.f,0.f,0.f};

    stage1(0, 0);
    __syncthreads();
    for (int kt = 0; kt < 27; ++kt) {
        int par = kt & 1;
        if (kt < 26) stage1(kt+1, par^1);       // issue next-step loads first
        int aB = par ? 24576 : 0;
        int bB = 49152 + (par ? 8192 : 0);
        bf16x8 a[3][2], b[4][2];
        #pragma unroll
        for (int kk = 0; kk < 2; ++kk) {
            int gof = ((kk*4 + lh) ^ l7) << 4;
            #pragma unroll
            for (int m = 0; m < 3; ++m)
                a[m][kk] = *(const bf16x8*)(smem + aB + (wid*48 + m*16 + rrow)*128 + gof);
            #pragma unroll
            for (int nf = 0; nf < 4; ++nf)
                b[nf][kk] = *(const bf16x8*)(smem + bB + (nf*16 + rrow)*128 + gof);
        }
        #pragma unroll
        for (int kk = 0; kk < 2; ++kk)
            #pragma unroll
            for (int m = 0; m < 3; ++m)
                #pragma unroll
                for (int nf = 0; nf < 4; ++nf)
                    acc1[m][nf] = __builtin_amdgcn_mfma_f32_16x16x32_bf16(
                        a[m][kk], b[nf][kk], acc1[m][nf], 0, 0, 0);
        __syncthreads();   // drains next-step stage (hidden under MFMA) + read fence
    }

    // phase2: 3 K-steps over hid channels. cw2 staged into A0; H @49152 (over B bufs).
    f32x4 acc2[3][4];
    #pragma unroll
    for (int m = 0; m < 3; ++m)
        #pragma unroll
        for (int nf = 0; nf < 4; ++nf) acc2[m][nf] = (f32x4){0.f,0.f,0.f,0.f};

    for (int kt2 = 0; kt2 < 3; ++kt2) {
        if (kt2) __syncthreads();
        #pragma unroll
        for (int s2 = 0; s2 < 6; ++s2) {
            int seg = wid*6 + s2;
            int row = seg*8 + (lane>>3);
            load_lds16(cw2b + (size_t)row*OC + kt2*64 + sgr, smem + seg*1024);
        }
        #pragma unroll
        for (int m = 0; m < 3; ++m) {
            int oc16 = wid*48 + m*16;
            if ((oc16 >> 6) == kt2) {
                int oc0 = oc16 + gcol*4;
                float4 bz = *(const float4*)&beff[oc0];
                int cb = (oc0 - kt2*64)*2;
                #pragma unroll
                for (int nf = 0; nf < 4; ++nf) {
                    int px = nf*16 + rrow;
                    ushort4 hv;
                    hv.x = f2bu(fmaxf(acc1[m][nf][0] + bz.x, 0.f));
                    hv.y = f2bu(fmaxf(acc1[m][nf][1] + bz.y, 0.f));
                    hv.z = f2bu(fmaxf(acc1[m][nf][2] + bz.z, 0.f));
                    hv.w = f2bu(fmaxf(acc1[m][nf][3] + bz.w, 0.f));
                    *(ushort4*)(smem + 49152 + px*136 + cb) = hv;
                }
            }
        }
        __syncthreads();
        #pragma unroll
        for (int kk = 0; kk < 2; ++kk) {
            int gofA = ((kk*4 + lh) ^ l7) << 4;
            int gofB = (kk*4 + lh) << 4;
            bf16x8 a2[3], b2[4];
            #pragma unroll
            for (int m2 = 0; m2 < 3; ++m2)
                a2[m2] = *(const bf16x8*)(smem + (wid*48 + m2*16 + rrow)*128 + gofA);
            #pragma unroll
            for (int nf = 0; nf < 4; ++nf)
                b2[nf] = *(const bf16x8*)(smem + 49152 + (nf*16 + rrow)*136 + gofB);
            #pragma unroll
            for (int m2 = 0; m2 < 3; ++m2)
                #pragma unroll
                for (int nf = 0; nf < 4; ++nf)
                    acc2[m2][nf] = __builtin_amdgcn_mfma_f32_16x16x32_bf16(
                        a2[m2], b2[nf], acc2[m2][nf], 0, 0, 0);
        }
    }

    #pragma unroll
    for (int m2 = 0; m2 < 3; ++m2) {
        int oc16 = wid*48 + m2*16;
        int sec = oc16 >> 6;
        int oc0 = oc16 + gcol*4;
        float4 cz = *(const float4*)&cb2[oc0];
        #pragma unroll
        for (int nf = 0; nf < 4; ++nf) {
            int px = nf*16 + rrow;
            int p = pb + px;
            ushort4 bv;
            bv.x = f2bu(fmaxf(acc2[m2][nf][0] + cz.x, 0.f));
            bv.y = f2bu(fmaxf(acc2[m2][nf][1] + cz.y, 0.f));
            bv.z = f2bu(fmaxf(acc2[m2][nf][2] + cz.z, 0.f));
            bv.w = f2bu(fmaxf(acc2[m2][nf][3] + cz.w, 0.f));
            if (sec == 0) {
                *(ushort4*)&qb16[((size_t)bn*PP + p)*64 + oc0] = bv;
            } else {
                int kv = sec - 1;
                int py = p / WW, pxx = p % WW;
                int d = oc0 - (sec << 6);
                *(ushort4*)&kvpad[((size_t)(bn*2+kv)*KVPA + (py+1)*KVPW + pxx+1)*64 + d] = bv;
                if (kv == 1)
                    *(ushort4*)&xvb16[((size_t)bn*PP + p)*64 + d] = bv;
            }
        }
    }
}

// K4a: MFMA conv3x3 64->64 on kvpad -> convb, T3-minimum pipelined (dbuf, 1 barrier/step)
__global__ __launch_bounds__(256) void k_kvgemm(const __hip_bfloat16* __restrict__ wA,
        const __hip_bfloat16* __restrict__ kvpad, const float* __restrict__ kvb,
        __hip_bfloat16* __restrict__ convb) {
    __shared__ __align__(16) char smem[49152];   // buf0 @0 24K, buf1 @24576 24K
    int tid = threadIdx.x;
    int wid = tid >> 6, lane = tid & 63;
    int tileN = blockIdx.x * 128;
    int bn2 = tileN / PP, p0 = tileN % PP;
    int sgr = ((lane&7) ^ (lane>>3)) * 8;

    size_t gbase[6];
    #pragma unroll
    for (int s2 = 0; s2 < 6; ++s2) {
        int seg = wid*6 + s2;
        if (seg < 8) {
            int row = seg*8 + (lane>>3);
            gbase[s2] = (size_t)row*576 + sgr;
        } else {
            int p = p0 + (seg-8)*8 + (lane>>3);
            int py = p / WW, px = p % WW;
            gbase[s2] = ((size_t)bn2*KVPA + (py+1)*KVPW + px+1)*64 + sgr;
        }
    }
    auto stage2 = [&](int kt, int par) {
        int dy = kt/3 - 1, dx = kt%3 - 1;
        int doff = dy*KVPW + dx;
        #pragma unroll
        for (int s2 = 0; s2 < 6; ++s2) {
            int seg = wid*6 + s2;
            const __hip_bfloat16* g = (seg < 8) ? wA + gbase[s2] + kt*64
                                                : kvpad + gbase[s2] + (size_t)doff*64;
            load_lds16(g, smem + par*24576 + seg*1024);
        }
    };
    int wr = wid >> 1, wc = wid & 1;
    int l7 = lane & 7, lh = lane >> 4;
    int arowb[2], browb[4];
    #pragma unroll
    for (int m = 0; m < 2; ++m)
        arowb[m] = (wr*32 + m*16 + (lane&15))*128;
    #pragma unroll
    for (int nf = 0; nf < 4; ++nf)
        browb[nf] = 8192 + (wc*64 + nf*16 + (lane&15))*128;

    f32x4 acc[2][4];
    #pragma unroll
    for (int m = 0; m < 2; ++m)
        #pragma unroll
        for (int nf = 0; nf < 4; ++nf) acc[m][nf] = (f32x4){0.f,0.f,0.f,0.f};

    stage2(0, 0);
    __syncthreads();
    for (int kt = 0; kt < 9; ++kt) {
        int par = kt & 1;
        if (kt < 8) stage2(kt+1, par^1);
        int po = par*24576;
        bf16x8 a[2][2], b[4][2];
        #pragma unroll
        for (int kk = 0; kk < 2; ++kk) {
            int gof = ((kk*4 + lh) ^ l7) << 4;
            #pragma unroll
            for (int m = 0; m < 2; ++m)
                a[m][kk] = *(const bf16x8*)(smem + po + arowb[m] + gof);
            #pragma unroll
            for (int nf = 0; nf < 4; ++nf)
                b[nf][kk] = *(const bf16x8*)(smem + po + browb[nf] + gof);
        }
        #pragma unroll
        for (int kk = 0; kk < 2; ++kk)
            #pragma unroll
            for (int m = 0; m < 2; ++m)
                #pragma unroll
                for (int nf = 0; nf < 4; ++nf)
                    acc[m][nf] = __builtin_amdgcn_mfma_f32_16x16x32_bf16(
                        a[m][kk], b[nf][kk], acc[m][nf], 0, 0, 0);
        __syncthreads();
    }
    #pragma unroll
    for (int m = 0; m < 2; ++m) {
        int rbase = wr*32 + m*16 + (lane>>4)*4;
        float4 bz = *(const float4*)&kvb[rbase];
        #pragma unroll
        for (int nf = 0; nf < 4; ++nf) {
            int col = p0 + wc*64 + nf*16 + (lane&15);
            ushort4 cv;
            cv.x = f2bu(fmaxf(acc[m][nf][0] + bz.x, 0.f));
            cv.y = f2bu(fmaxf(acc[m][nf][1] + bz.y, 0.f));
            cv.z = f2bu(fmaxf(acc[m][nf][2] + bz.z, 0.f));
            cv.w = f2bu(fmaxf(acc[m][nf][3] + bz.w, 0.f));
            *(ushort4*)&convb[((size_t)bn2*PP + col)*64 + rbase] = cv;
        }
    }
}

// K4b: 3x3 avgpool on convb -> kbufb bf16 [bn][k][d], vbufT bf16 [bn][d][k]
__global__ __launch_bounds__(256) void k_pool(const __hip_bfloat16* __restrict__ convb,
        __hip_bfloat16* __restrict__ kbufb, __hip_bfloat16* __restrict__ vbufT) {
    int idx = blockIdx.x*256 + threadIdx.x;
    int dg = idx % 8; idx /= 8;
    int pp = idx % PK; idx /= PK;
    int bn2 = idx;
    int kv = bn2 & 1, bn = bn2 >> 1;
    int qy = pp / KHW, qx = pp % KHW;
    float s[8] = {0,0,0,0,0,0,0,0};
    const __hip_bfloat16* base = convb + (size_t)bn2*PP*64 + dg*8;
    #pragma unroll
    for (int sy = 0; sy < 3; ++sy)
        #pragma unroll
        for (int sx = 0; sx < 3; ++sx) {
            union { bf16x8 v; unsigned short h[8]; } c;
            c.v = *(const bf16x8*)(base + ((size_t)(qy*3+sy)*WW + qx*3+sx)*64);
            #pragma unroll
            for (int j = 0; j < 8; ++j) s[j] += bu2f(c.h[j]);
        }
    if (kv == 0) {
        union { ushort4 u[2]; unsigned short h[8]; } cv;
        #pragma unroll
        for (int j = 0; j < 8; ++j) cv.h[j] = f2bu(s[j] * (1.f/9.f));
        ushort4* dst = (ushort4*)(kbufb + ((size_t)bn*PK + pp)*64 + dg*8);
        dst[0] = cv.u[0]; dst[1] = cv.u[1];
    } else {
        #pragma unroll
        for (int j = 0; j < 8; ++j)
            vbufT[((size_t)bn*64 + dg*8 + j)*PK + pp] = __float2bfloat16(s[j]*(1.f/81.f));
    }
}

// K5: fused MFMA leave-one-out sigmoid attention + output MLP.
// Block = (bn, 64-query tile). Full 1280 keys per block; then in-block epilogue:
// R = relu(attn + sc*xv) -> GEMM1(W1)+relu -> GEMM2(W2)+relu -> out.
// LDS 40KB: Qs@0, Ks@8192(->Rs), Vs@16384(->W1s), Ps@24576(->W2s), XVs@32768(->Ts).
__global__ __launch_bounds__(256) void k_attn4(const __hip_bfloat16* __restrict__ qb16,
        const __hip_bfloat16* __restrict__ kbufb, const __hip_bfloat16* __restrict__ vbufT,
        const __hip_bfloat16* __restrict__ xvb16, const float* __restrict__ scales,
        const __hip_bfloat16* __restrict__ w1sw, const __hip_bfloat16* __restrict__ w2sw,
        const float* __restrict__ b1, const float* __restrict__ b2,
        float* __restrict__ out) {
    __shared__ __align__(16) char smem[40960];
    char* Qs  = smem;
    char* Ks  = smem + 8192;    // -> Rs
    char* Vs  = smem + 16384;   // -> W1s
    char* Ps  = smem + 24576;   // -> W2s
    char* XVs = smem + 32768;   // -> Ts
    int tid = threadIdx.x;
    int wid = tid >> 6, lane = tid & 63;
    int qt = blockIdx.x % 36;
    int bn = blockIdx.x / 36;
    int b = bn / NVIEW, n = bn % NVIEW;
    int p0 = qt*64;
    float sc = scales[n];

    {   // stage Q and XV (same [p][d] layout, pre-swizzled source)
        const char* gq  = (const char*)(qb16  + ((size_t)bn*PP + p0)*64);
        const char* gxv = (const char*)(xvb16 + ((size_t)bn*PP + p0)*64);
        #pragma unroll
        for (int i = 0; i < 2; ++i) {
            int s = wid*2 + i;
            int lin = s*1024 + lane*16;
            int r = lin >> 7, c = (lin >> 4) & 7;
            int gof = (r<<7) + ((c ^ (r&7)) << 4);
            load_lds16(gq + gof, Qs + s*1024);
            load_lds16(gxv + gof, XVs + s*1024);
        }
    }
    int arow = wid*16 + (lane&15);
    int brow = lane&15;
    int gcol = lane>>4;
    int vrow = tid >> 2;
    int vc2 = (tid & 3) * 2;

    f32x4 oacc[4];
    #pragma unroll
    for (int i = 0; i < 4; ++i) oacc[i] = (f32x4){0,0,0,0};

    for (int mi = 0; mi < NVIEW-1; ++mi) {
        int m = mi + (mi >= n ? 1 : 0);
        int bnk = b*NVIEW + m;
        const char* gk = (const char*)(kbufb + (size_t)bnk*PK*64);
        const __hip_bfloat16* gv = vbufT + (size_t)bnk*64*PK;
        for (int kc = 0; kc < 4; ++kc) {
            __syncthreads();
            #pragma unroll
            for (int i = 0; i < 2; ++i) {
                int s = wid*2 + i;
                int lin = s*1024 + lane*16;
                int r = lin >> 7, c = (lin >> 4) & 7;
                int gof = (r<<7) + ((c ^ (r&7)) << 4);
                load_lds16(gk + (size_t)kc*8192 + gof, Ks + s*1024);
            }
            {
                const __hip_bfloat16* src = gv + vrow*PK + kc*64 + vc2*8;
                bf16x8 v0 = *(const bf16x8*)src;
                bf16x8 v1 = *(const bf16x8*)(src+8);
                *(bf16x8*)(Vs + vrow*128 + ((vc2 ^ (vrow&7))<<4)) = v0;
                *(bf16x8*)(Vs + vrow*128 + (((vc2+1) ^ (vrow&7))<<4)) = v1;
            }
            __syncthreads();
            f32x4 sacc[4];
            #pragma unroll
            for (int i = 0; i < 4; ++i) sacc[i] = (f32x4){0,0,0,0};
            #pragma unroll
            for (int kk = 0; kk < 2; ++kk) {
                int g = kk*4 + gcol;
                bf16x8 af = *(const bf16x8*)(Ks + arow*128 + ((g ^ (arow&7))<<4));
                #pragma unroll
                for (int nf = 0; nf < 4; ++nf) {
                    int q = nf*16 + brow;
                    bf16x8 bq = *(const bf16x8*)(Qs + q*128 + ((g ^ (q&7))<<4));
                    sacc[nf] = __builtin_amdgcn_mfma_f32_16x16x32_bf16(af, bq, sacc[nf], 0,0,0);
                }
            }
            {
                int kbase = wid*16 + gcol*4;
                #pragma unroll
                for (int nf = 0; nf < 4; ++nf) {
                    int q = nf*16 + brow;
                    ushort4 pu;
                    float e0 = __expf(-sacc[nf][0]*0.125f);
                    float e1 = __expf(-sacc[nf][1]*0.125f);
                    float e2 = __expf(-sacc[nf][2]*0.125f);
                    float e3 = __expf(-sacc[nf][3]*0.125f);
                    pu.x = f2bu(__builtin_amdgcn_rcpf(1.f+e0));
                    pu.y = f2bu(__builtin_amdgcn_rcpf(1.f+e1));
                    pu.z = f2bu(__builtin_amdgcn_rcpf(1.f+e2));
                    pu.w = f2bu(__builtin_amdgcn_rcpf(1.f+e3));
                    *(ushort4*)(Ps + q*128 + (((kbase>>3) ^ (q&7))<<4) + (kbase&7)*2) = pu;
                }
            }
            __syncthreads();
            #pragma unroll
            for (int kk = 0; kk < 2; ++kk) {
                int g = kk*4 + gcol;
                int qr = wid*16 + brow;
                bf16x8 pf = *(const bf16x8*)(Ps + qr*128 + ((g ^ (qr&7))<<4));
                #pragma unroll
                for (int nf = 0; nf < 4; ++nf) {
                    int d = nf*16 + brow;
                    bf16x8 vf = *(const bf16x8*)(Vs + d*128 + ((g ^ (d&7))<<4));
                    oacc[nf] = __builtin_amdgcn_mfma_f32_16x16x32_bf16(pf, vf, oacc[nf], 0,0,0);
                }
            }
        }
    }

    // ---- fused epilogue ----
    __syncthreads();   // all attn LDS reads done; safe to repurpose Ks/Vs/Ps
    #pragma unroll
    for (int i = 0; i < 4; ++i) {
        int seg = wid*4 + i;
        const char* src = (seg < 8) ? (const char*)w1sw + seg*1024
                                    : (const char*)w2sw + (seg-8)*1024;
        load_lds16(src + lane*16, ((seg < 8) ? Vs : Ps) + (seg & 7)*1024);
    }
    #pragma unroll
    for (int nf = 0; nf < 4; ++nf) {
        int d = nf*16 + brow;
        #pragma unroll
        for (int r = 0; r < 4; ++r) {
            int q = wid*16 + gcol*4 + r;
            int off = q*128 + (((d>>3) ^ (q&7))<<4) + (d&7)*2;
            float xv = bu2f(*(const unsigned short*)(XVs + off));
            *(unsigned short*)(Ks + off) = f2bu(fmaxf(oacc[nf][r] + sc*xv, 0.f));
        }
    }
    __syncthreads();
    f32x4 acc1[4];
    #pragma unroll
    for (int nf = 0; nf < 4; ++nf) acc1[nf] = (f32x4){0,0,0,0};
    #pragma unroll
    for (int kk = 0; kk < 2; ++kk) {
        int g = kk*4 + gcol;
        int oc = wid*16 + brow;
        bf16x8 af = *(const bf16x8*)(Vs + oc*128 + ((g ^ (oc&7)) << 4));
        #pragma unroll
        for (int nf = 0; nf < 4; ++nf) {
            int px = nf*16 + brow;
            bf16x8 bf = *(const bf16x8*)(Ks + px*128 + ((g ^ (px&7)) << 4));
            acc1[nf] = __builtin_amdgcn_mfma_f32_16x16x32_bf16(af, bf, acc1[nf], 0,0,0);
        }
    }
    {
        int oc0 = wid*16 + gcol*4;
        float4 bz = *(const float4*)&b1[oc0];
        #pragma unroll
        for (int nf = 0; nf < 4; ++nf) {
            int px = nf*16 + brow;
            ushort4 tv;
            tv.x = f2bu(fmaxf(acc1[nf][0] + bz.x, 0.f));
            tv.y = f2bu(fmaxf(acc1[nf][1] + bz.y, 0.f));
            tv.z = f2bu(fmaxf(acc1[nf][2] + bz.z, 0.f));
            tv.w = f2bu(fmaxf(acc1[nf][3] + bz.w, 0.f));
            *(ushort4*)(XVs + px*128 + (((oc0>>3) ^ (px&7)) << 4) + (oc0&7)*2) = tv;
        }
    }
    __syncthreads();
    f32x4 acc2[4];
    #pragma unroll
    for (int nf = 0; nf < 4; ++nf) acc2[nf] = (f32x4){0,0,0,0};
    #pragma unroll
    for (int kk = 0; kk < 2; ++kk) {
        int g = kk*4 + gcol;
        int oc = wid*16 + brow;
        bf16x8 af = *(const bf16x8*)(Ps + oc*128 + ((g ^ (oc&7)) << 4));
        #pragma unroll
        for (int nf = 0; nf < 4; ++nf) {
            int px = nf*16 + brow;
            bf16x8 bf = *(const bf16x8*)(XVs + px*128 + ((g ^ (px&7)) << 4));
            acc2[nf] = __builtin_amdgcn_mfma_f32_16x16x32_bf16(af, bf, acc2[nf], 0,0,0);
        }
    }
    {
        int oc0 = wid*16 + gcol*4;
        float4 bz = *(const float4*)&b2[oc0];
        #pragma unroll
        for (int nf = 0; nf < 4; ++nf) {
            int px = nf*16 + brow;
            float* dst = out + ((size_t)bn*64 + oc0)*PP + p0 + px;
            dst[0*PP] = fmaxf(acc2[nf][0] + bz.x, 0.f);
            dst[1*PP] = fmaxf(acc2[nf][1] + bz.y, 0.f);
            dst[2*PP] = fmaxf(acc2[nf][2] + bz.z, 0.f);
            dst[3*PP] = fmaxf(acc2[nf][3] + bz.w, 0.f);
        }
    }
}

extern "C" void kernel_launch(void* const* d_in, const int* in_sizes, int n_in,
                              void* d_out, int out_size, void* d_ws, size_t ws_size,
                              hipStream_t stream) {
    (void)in_sizes; (void)n_in; (void)out_size; (void)ws_size;
    const float* x      = (const float*)d_in[0];
    const float* pa_w1  = (const float*)d_in[1];
    const float* pa_b1  = (const float*)d_in[2];
    const float* pa_w2  = (const float*)d_in[3];
    const float* pa_b2  = (const float*)d_in[4];
    const float* pa_w3  = (const float*)d_in[5];
    const float* pa_b3  = (const float*)d_in[6];
    const float* pa_cw1 = (const float*)d_in[7];
    const float* pa_cb1 = (const float*)d_in[8];
    const float* pa_cw2 = (const float*)d_in[9];
    const float* pa_cb2 = (const float*)d_in[10];
    const float* kv_w   = (const float*)d_in[11];
    const float* kv_b   = (const float*)d_in[12];
    const float* out_w1 = (const float*)d_in[13];
    const float* out_b1 = (const float*)d_in[14];
    const float* out_w2 = (const float*)d_in[15];
    const float* out_b2 = (const float*)d_in[16];
    const float* scales = (const float*)d_in[17];
    float* out = (float*)d_out;
    float* ws  = (float*)d_ws;

    __hip_bfloat16* weffb = (__hip_bfloat16*)(ws + OFF_WEFFB);
    float* beff = ws + OFF_BEFF;
    __hip_bfloat16* cw2b  = (__hip_bfloat16*)(ws + OFF_CW2B);
    __hip_bfloat16* wkvb  = (__hip_bfloat16*)(ws + OFF_WKVB);
    __hip_bfloat16* padxT = (__hip_bfloat16*)(ws + OFF_PADXT);
    __hip_bfloat16* qb16  = (__hip_bfloat16*)(ws + OFF_QB16);
    __hip_bfloat16* kbufb = (__hip_bfloat16*)(ws + OFF_KB16);
    __hip_bfloat16* vbufT = (__hip_bfloat16*)(ws + OFF_VB16T);
    __hip_bfloat16* kvpad = (__hip_bfloat16*)(ws + OFF_KVPAD);
    __hip_bfloat16* convb = (__hip_bfloat16*)(ws + OFF_CONVB);
    __hip_bfloat16* w1sw  = (__hip_bfloat16*)(ws + OFF_W1SW);
    __hip_bfloat16* w2sw  = (__hip_bfloat16*)(ws + OFF_W2SW);
    __hip_bfloat16* xvb16 = (__hip_bfloat16*)(ws + OFF_XVB16);

    k_fold<<<216, 192, 0, stream>>>(pa_cw1, pa_cb1, pa_w1, pa_b1,
                                    pa_w2, pa_b2, pa_w3, pa_b3, weffb, beff);
    k_wprep<<<339, 256, 0, stream>>>(kv_w, pa_cw2, out_w1, out_w2,
                                     wkvb, cw2b, w1sw, w2sw, kvpad);
    k_padxT<<<(BN*PADA+255)/256, 256, 0, stream>>>(x, padxT);
    k_mfc<<<NTOT/64, 256, 0, stream>>>(weffb, padxT, cw2b, beff, pa_cb2,
                                       xvb16, qb16, kvpad);
    k_kvgemm<<<BN*2*PP/128, 256, 0, stream>>>(wkvb, kvpad, kv_b, convb);
    k_pool<<<BN*2*PK*8/256, 256, 0, stream>>>(convb, kbufb, vbufT);
    k_attn4<<<BN*36, 256, 0, stream>>>(qb16, kbufb, vbufT, xvb16, scales,
                                       w1sw, w2sw, out_b1, out_b2, out);
}

// Round 16
// 104.248 us; speedup vs baseline: 1.0923x; 1.0699x over previous
//
#include <hip/hip_runtime.h>
#include <hip/hip_bf16.h>
#include <math.h>

#define BB 2
#define NVIEW 6
#define BN 12
#define CIN 64
#define HH 48
#define WW 48
#define PP (HH*WW)        // 2304
#define OC 192
#define HPA 192
#define HIDP 64
#define KHW 16
#define PK 256
#define PADW 54
#define PADA (PADW*PADW)  // 2916
#define NTOT (BN*PP)      // 27648
#define K1 1728           // 27 taps * 64 ic
#define KVPW 50
#define KVPA (KVPW*KVPW)  // 2500

typedef __attribute__((ext_vector_type(8))) short bf16x8;
typedef __attribute__((ext_vector_type(4))) float f32x4;

// ---- workspace layout (float elements) ----
#define OFF_WEFFB 0
#define SZ_WEFFB_FL (OC*K1/2)              // 165888
#define OFF_BEFF (OFF_WEFFB + SZ_WEFFB_FL)
#define SZ_BEFF 256
#define OFF_CW2B (OFF_BEFF + SZ_BEFF)
#define SZ_CW2B_FL (OC*OC/2)               // 18432
#define OFF_WKVB (OFF_CW2B + SZ_CW2B_FL)
#define SZ_WKVB_FL (64*576/2)              // 18432
#define OFF_PADXT (OFF_WKVB + SZ_WKVB_FL)
#define SZ_PADXT_FL (BN*PADA*64/2)         // 1119744
#define OFF_QB16 (OFF_PADXT + SZ_PADXT_FL)
#define SZ_QB16_FL (BN*PP*64/2)            // 884736
#define OFF_KB16 (OFF_QB16 + SZ_QB16_FL)
#define SZ_KB16_FL (BN*PK*64/2)            // 98304
#define OFF_VB16T (OFF_KB16 + SZ_KB16_FL)
#define SZ_VB16T_FL (BN*64*PK/2)           // 98304
#define OFF_KVPAD (OFF_VB16T + SZ_VB16T_FL)
#define SZ_KVPAD_FL (BN*2*KVPA*64/2)       // 1920000
#define OFF_CONVB (OFF_KVPAD + SZ_KVPAD_FL)
#define SZ_CONVB_FL (BN*2*PP*64/2)         // 1769472
#define OFF_W1SW (OFF_CONVB + SZ_CONVB_FL)
#define SZ_WSW_FL 2048                     // 4096 bf16
#define OFF_W2SW (OFF_W1SW + SZ_WSW_FL)
#define OFF_XVB16 (OFF_W2SW + SZ_WSW_FL)
#define SZ_XVB16_FL (BN*PP*64/2)           // 884736 (bf16 [bn][p][d])

// k_prep grid split
#define PREP_FOLD_BLOCKS 216
#define PREP_WPREP_BLOCKS 452              // 86624 items / 192
#define PREP_PADXT_BLOCKS 183              // 34992 items / 192
#define PREP_BLOCKS (PREP_FOLD_BLOCKS + PREP_WPREP_BLOCKS + PREP_PADXT_BLOCKS)

__device__ __forceinline__ void load_lds16(const void* g, void* l) {
    __builtin_amdgcn_global_load_lds(
        (const __attribute__((address_space(1))) unsigned int*)g,
        (__attribute__((address_space(3))) unsigned int*)l, 16, 0, 0);
}

__device__ __forceinline__ unsigned short f2bu(float f) {
    __hip_bfloat16 h = __float2bfloat16(f);
    return *(unsigned short*)&h;
}

__device__ __forceinline__ float bu2f(unsigned short h) {
    unsigned int u = ((unsigned int)h) << 16;
    return *(float*)&u;
}

// K1: merged prep. blocks [0,216): fold; [216,668): wprep+halo; [668,851): padxT.
__global__ __launch_bounds__(192) void k_prep(const float* __restrict__ cw1,
                       const float* __restrict__ cb1,
                       const float* __restrict__ w1, const float* __restrict__ b1,
                       const float* __restrict__ w2, const float* __restrict__ b2,
                       const float* __restrict__ w3, const float* __restrict__ b3,
                       const float* __restrict__ kvw, const float* __restrict__ cw2,
                       const float* __restrict__ ow1, const float* __restrict__ ow2,
                       const float* __restrict__ x,
                       __hip_bfloat16* __restrict__ weffb, float* __restrict__ beff,
                       __hip_bfloat16* __restrict__ wkvb, __hip_bfloat16* __restrict__ cw2b,
                       __hip_bfloat16* __restrict__ w1sw, __hip_bfloat16* __restrict__ w2sw,
                       __hip_bfloat16* __restrict__ kvpad,
                       __hip_bfloat16* __restrict__ padxT) {
    __shared__ float cw1s[8][HPA];
    int blk = blockIdx.x;
    int tid = threadIdx.x;
    if (blk < PREP_FOLD_BLOCKS) {
        // ---- fold ----
        int r = blk / 72;
        int rem = blk % 72;
        int og = rem / 3, tz = rem % 3;
        int tg = tz*192 + tid;
        int ic = tg / 9, tap = tg % 9;
        const float* w = (r==0) ? w1 : (r==1) ? w2 : w3;
        #pragma unroll
        for (int j = 0; j < 8; ++j)
            cw1s[j][tid] = cw1[(size_t)(og*8+j)*(HPA*3) + r*HPA + tid];
        __syncthreads();
        float acc[8] = {0,0,0,0,0,0,0,0};
        for (int c = 0; c < HPA; ++c) {
            float wv = w[(size_t)c*(CIN*9) + tg];
            #pragma unroll
            for (int j = 0; j < 8; ++j)
                acc[j] += cw1s[j][c] * wv;
        }
        #pragma unroll
        for (int j = 0; j < 8; ++j)
            weffb[(size_t)(og*8+j)*K1 + r*576 + tap*64 + ic] = __float2bfloat16(acc[j]);
        if (r == 0 && tz == 0 && tid < 8) {
            int o = og*8 + tid;
            float bacc = cb1[o];
            for (int rr = 0; rr < 3; ++rr) {
                const float* bb = (rr==0)?b1:(rr==1)?b2:b3;
                for (int c = 0; c < HPA; ++c)
                    bacc += cw1[(size_t)o*(HPA*3) + rr*HPA + c] * bb[c];
            }
            beff[o] = bacc;
        }
    } else if (blk < PREP_FOLD_BLOCKS + PREP_WPREP_BLOCKS) {
        // ---- wprep + kvpad halo ----
        int idx = (blk - PREP_FOLD_BLOCKS)*192 + tid;
        if (idx < 36864) {
            int oc = idx / 576, rest = idx % 576;
            int tap = rest / 64, ic = rest % 64;
            wkvb[idx] = __float2bfloat16(kvw[(oc*64 + ic)*9 + tap]);
        } else if (idx < 73728) {
            int i = idx - 36864;
            cw2b[i] = __float2bfloat16(cw2[i]);
        } else if (idx < 81920) {
            int i = idx - 73728;
            const float* w = (i < 4096) ? ow1 : ow2;
            __hip_bfloat16* dst = (i < 4096) ? w1sw : w2sw;
            int j = i & 4095;
            int oc = j >> 6, s = (j >> 3) & 7, e = j & 7;
            int k = ((s ^ (oc & 7)) << 3) + e;
            dst[j] = __float2bfloat16(w[oc*64 + k]);
        } else if (idx < 86624) {
            int i = idx - 81920;
            int bn2 = i / 196, h = i % 196;
            int py, px;
            if (h < 50)       { py = 0;        px = h; }
            else if (h < 100) { py = 49;       px = h - 50; }
            else if (h < 148) { py = h - 99;   px = 0; }
            else              { py = h - 147;  px = 49; }
            bf16x8 z = (bf16x8){0,0,0,0,0,0,0,0};
            __hip_bfloat16* dst = kvpad + ((size_t)bn2*KVPA + py*KVPW + px)*64;
            #pragma unroll
            for (int j = 0; j < 8; ++j) *(bf16x8*)(dst + j*8) = z;
        }
    } else {
        // ---- padxT ----
        int idx = (blk - PREP_FOLD_BLOCKS - PREP_WPREP_BLOCKS)*192 + tid;
        if (idx >= BN*PADA) return;
        int spos = idx % PADA; int bn = idx / PADA;
        int sy = spos / PADW, sx = spos % PADW;
        __hip_bfloat16* dst = padxT + (size_t)idx*64;
        if (sy >= 3 && sy < 51 && sx >= 3 && sx < 51) {
            const float* src = x + (size_t)bn*CIN*PP + (sy-3)*WW + (sx-3);
            #pragma unroll 8
            for (int ic = 0; ic < 64; ++ic) dst[ic] = __float2bfloat16(src[ic*PP]);
        } else {
            #pragma unroll 8
            for (int ic = 0; ic < 64; ++ic) dst[ic] = __float2bfloat16(0.f);
        }
    }
}

// K_MFC: fused MultiFieldConv, T3-minimum pipelined: double-buffered stage issued
// BEFORE current step's compute, ONE barrier per K-step.
// LDS 64KB: A0@0 24K, A1@24576 24K, B0@49152 8K, B1@57344 8K; H @49152 (phase2).
__global__ __launch_bounds__(256) void k_mfc(const __hip_bfloat16* __restrict__ wA,
        const __hip_bfloat16* __restrict__ pxT, const __hip_bfloat16* __restrict__ cw2b,
        const float* __restrict__ beff, const float* __restrict__ cb2,
        __hip_bfloat16* __restrict__ xvb16, __hip_bfloat16* __restrict__ qb16,
        __hip_bfloat16* __restrict__ kvpad) {
    __shared__ __align__(16) char smem[65536];
    int tid = threadIdx.x;
    int wid = tid >> 6, lane = tid & 63;
    int bn = blockIdx.x / 36;
    int pb = (blockIdx.x % 36) * 64;
    int sgr = ((lane&7) ^ (lane>>3)) * 8;     // pre-swizzled source granule
    int l7 = lane & 7, lh = lane >> 4, rrow = lane & 15, gcol = lane >> 4;

    size_t gbase[8];
    int dbase[8];
    #pragma unroll
    for (int s2 = 0; s2 < 8; ++s2) {
        int seg = wid*8 + s2;
        if (seg < 24) {
            int row = seg*8 + (lane>>3);
            gbase[s2] = (size_t)row*K1 + sgr;
            dbase[s2] = seg*1024;
        } else {
            int p = pb + (seg-24)*8 + (lane>>3);
            int py = p / WW, px = p % WW;
            gbase[s2] = ((size_t)bn*PADA + (py+3)*PADW + (px+3))*64 + sgr;
            dbase[s2] = 49152 + (seg-24)*1024;
        }
    }

    auto stage1 = [&](int kt, int par) {
        int r_ = kt / 9, tap = kt - r_*9;
        int doff = (r_+1)*((tap/3 - 1)*PADW + (tap%3 - 1));
        int poA = par ? 24576 : 0;
        int poB = par ? 8192 : 0;
        #pragma unroll
        for (int s2 = 0; s2 < 8; ++s2) {
            int seg = wid*8 + s2;
            const __hip_bfloat16* g = (seg < 24) ? wA + gbase[s2] + kt*64
                                                 : pxT + gbase[s2] + (size_t)doff*64;
            load_lds16(g, smem + dbase[s2] + ((seg < 24) ? poA : poB));
        }
    };

    f32x4 acc1[3][4];
    #pragma unroll
    for (int m = 0; m < 3; ++m)
        #pragma unroll
        for (int nf = 0; nf < 4; ++nf) acc1[m][nf] = (f32x4){0.f,0.f,0.f,0.f};

    stage1(0, 0);
    __syncthreads();
    for (int kt = 0; kt < 27; ++kt) {
        int par = kt & 1;
        if (kt < 26) stage1(kt+1, par^1);       // issue next-step loads first
        int aB = par ? 24576 : 0;
        int bB = 49152 + (par ? 8192 : 0);
        bf16x8 a[3][2], b[4][2];
        #pragma unroll
        for (int kk = 0; kk < 2; ++kk) {
            int gof = ((kk*4 + lh) ^ l7) << 4;
            #pragma unroll
            for (int m = 0; m < 3; ++m)
                a[m][kk] = *(const bf16x8*)(smem + aB + (wid*48 + m*16 + rrow)*128 + gof);
            #pragma unroll
            for (int nf = 0; nf < 4; ++nf)
                b[nf][kk] = *(const bf16x8*)(smem + bB + (nf*16 + rrow)*128 + gof);
        }
        #pragma unroll
        for (int kk = 0; kk < 2; ++kk)
            #pragma unroll
            for (int m = 0; m < 3; ++m)
                #pragma unroll
                for (int nf = 0; nf < 4; ++nf)
                    acc1[m][nf] = __builtin_amdgcn_mfma_f32_16x16x32_bf16(
                        a[m][kk], b[nf][kk], acc1[m][nf], 0, 0, 0);
        __syncthreads();   // drains next-step stage (hidden under MFMA) + read fence
    }

    // phase2: 3 K-steps over hid channels. cw2 staged into A0; H @49152 (over B bufs).
    f32x4 acc2[3][4];
    #pragma unroll
    for (int m = 0; m < 3; ++m)
        #pragma unroll
        for (int nf = 0; nf < 4; ++nf) acc2[m][nf] = (f32x4){0.f,0.f,0.f,0.f};

    for (int kt2 = 0; kt2 < 3; ++kt2) {
        if (kt2) __syncthreads();
        #pragma unroll
        for (int s2 = 0; s2 < 6; ++s2) {
            int seg = wid*6 + s2;
            int row = seg*8 + (lane>>3);
            load_lds16(cw2b + (size_t)row*OC + kt2*64 + sgr, smem + seg*1024);
        }
        #pragma unroll
        for (int m = 0; m < 3; ++m) {
            int oc16 = wid*48 + m*16;
            if ((oc16 >> 6) == kt2) {
                int oc0 = oc16 + gcol*4;
                float4 bz = *(const float4*)&beff[oc0];
                int cb = (oc0 - kt2*64)*2;
                #pragma unroll
                for (int nf = 0; nf < 4; ++nf) {
                    int px = nf*16 + rrow;
                    ushort4 hv;
                    hv.x = f2bu(fmaxf(acc1[m][nf][0] + bz.x, 0.f));
                    hv.y = f2bu(fmaxf(acc1[m][nf][1] + bz.y, 0.f));
                    hv.z = f2bu(fmaxf(acc1[m][nf][2] + bz.z, 0.f));
                    hv.w = f2bu(fmaxf(acc1[m][nf][3] + bz.w, 0.f));
                    *(ushort4*)(smem + 49152 + px*136 + cb) = hv;
                }
            }
        }
        __syncthreads();
        #pragma unroll
        for (int kk = 0; kk < 2; ++kk) {
            int gofA = ((kk*4 + lh) ^ l7) << 4;
            int gofB = (kk*4 + lh) << 4;
            bf16x8 a2[3], b2[4];
            #pragma unroll
            for (int m2 = 0; m2 < 3; ++m2)
                a2[m2] = *(const bf16x8*)(smem + (wid*48 + m2*16 + rrow)*128 + gofA);
            #pragma unroll
            for (int nf = 0; nf < 4; ++nf)
                b2[nf] = *(const bf16x8*)(smem + 49152 + (nf*16 + rrow)*136 + gofB);
            #pragma unroll
            for (int m2 = 0; m2 < 3; ++m2)
                #pragma unroll
                for (int nf = 0; nf < 4; ++nf)
                    acc2[m2][nf] = __builtin_amdgcn_mfma_f32_16x16x32_bf16(
                        a2[m2], b2[nf], acc2[m2][nf], 0, 0, 0);
        }
    }

    #pragma unroll
    for (int m2 = 0; m2 < 3; ++m2) {
        int oc16 = wid*48 + m2*16;
        int sec = oc16 >> 6;
        int oc0 = oc16 + gcol*4;
        float4 cz = *(const float4*)&cb2[oc0];
        #pragma unroll
        for (int nf = 0; nf < 4; ++nf) {
            int px = nf*16 + rrow;
            int p = pb + px;
            ushort4 bv;
            bv.x = f2bu(fmaxf(acc2[m2][nf][0] + cz.x, 0.f));
            bv.y = f2bu(fmaxf(acc2[m2][nf][1] + cz.y, 0.f));
            bv.z = f2bu(fmaxf(acc2[m2][nf][2] + cz.z, 0.f));
            bv.w = f2bu(fmaxf(acc2[m2][nf][3] + cz.w, 0.f));
            if (sec == 0) {
                *(ushort4*)&qb16[((size_t)bn*PP + p)*64 + oc0] = bv;
            } else {
                int kv = sec - 1;
                int py = p / WW, pxx = p % WW;
                int d = oc0 - (sec << 6);
                *(ushort4*)&kvpad[((size_t)(bn*2+kv)*KVPA + (py+1)*KVPW + pxx+1)*64 + d] = bv;
                if (kv == 1)
                    *(ushort4*)&xvb16[((size_t)bn*PP + p)*64 + d] = bv;
            }
        }
    }
}

// K4a: MFMA conv3x3 64->64 on kvpad -> convb, T3-minimum pipelined (dbuf, 1 barrier/step)
__global__ __launch_bounds__(256) void k_kvgemm(const __hip_bfloat16* __restrict__ wA,
        const __hip_bfloat16* __restrict__ kvpad, const float* __restrict__ kvb,
        __hip_bfloat16* __restrict__ convb) {
    __shared__ __align__(16) char smem[49152];   // buf0 @0 24K, buf1 @24576 24K
    int tid = threadIdx.x;
    int wid = tid >> 6, lane = tid & 63;
    int tileN = blockIdx.x * 128;
    int bn2 = tileN / PP, p0 = tileN % PP;
    int sgr = ((lane&7) ^ (lane>>3)) * 8;

    size_t gbase[6];
    #pragma unroll
    for (int s2 = 0; s2 < 6; ++s2) {
        int seg = wid*6 + s2;
        if (seg < 8) {
            int row = seg*8 + (lane>>3);
            gbase[s2] = (size_t)row*576 + sgr;
        } else {
            int p = p0 + (seg-8)*8 + (lane>>3);
            int py = p / WW, px = p % WW;
            gbase[s2] = ((size_t)bn2*KVPA + (py+1)*KVPW + px+1)*64 + sgr;
        }
    }
    auto stage2 = [&](int kt, int par) {
        int dy = kt/3 - 1, dx = kt%3 - 1;
        int doff = dy*KVPW + dx;
        #pragma unroll
        for (int s2 = 0; s2 < 6; ++s2) {
            int seg = wid*6 + s2;
            const __hip_bfloat16* g = (seg < 8) ? wA + gbase[s2] + kt*64
                                                : kvpad + gbase[s2] + (size_t)doff*64;
            load_lds16(g, smem + par*24576 + seg*1024);
        }
    };
    int wr = wid >> 1, wc = wid & 1;
    int l7 = lane & 7, lh = lane >> 4;
    int arowb[2], browb[4];
    #pragma unroll
    for (int m = 0; m < 2; ++m)
        arowb[m] = (wr*32 + m*16 + (lane&15))*128;
    #pragma unroll
    for (int nf = 0; nf < 4; ++nf)
        browb[nf] = 8192 + (wc*64 + nf*16 + (lane&15))*128;

    f32x4 acc[2][4];
    #pragma unroll
    for (int m = 0; m < 2; ++m)
        #pragma unroll
        for (int nf = 0; nf < 4; ++nf) acc[m][nf] = (f32x4){0.f,0.f,0.f,0.f};

    stage2(0, 0);
    __syncthreads();
    for (int kt = 0; kt < 9; ++kt) {
        int par = kt & 1;
        if (kt < 8) stage2(kt+1, par^1);
        int po = par*24576;
        bf16x8 a[2][2], b[4][2];
        #pragma unroll
        for (int kk = 0; kk < 2; ++kk) {
            int gof = ((kk*4 + lh) ^ l7) << 4;
            #pragma unroll
            for (int m = 0; m < 2; ++m)
                a[m][kk] = *(const bf16x8*)(smem + po + arowb[m] + gof);
            #pragma unroll
            for (int nf = 0; nf < 4; ++nf)
                b[nf][kk] = *(const bf16x8*)(smem + po + browb[nf] + gof);
        }
        #pragma unroll
        for (int kk = 0; kk < 2; ++kk)
            #pragma unroll
            for (int m = 0; m < 2; ++m)
                #pragma unroll
                for (int nf = 0; nf < 4; ++nf)
                    acc[m][nf] = __builtin_amdgcn_mfma_f32_16x16x32_bf16(
                        a[m][kk], b[nf][kk], acc[m][nf], 0, 0, 0);
        __syncthreads();
    }
    #pragma unroll
    for (int m = 0; m < 2; ++m) {
        int rbase = wr*32 + m*16 + (lane>>4)*4;
        float4 bz = *(const float4*)&kvb[rbase];
        #pragma unroll
        for (int nf = 0; nf < 4; ++nf) {
            int col = p0 + wc*64 + nf*16 + (lane&15);
            ushort4 cv;
            cv.x = f2bu(fmaxf(acc[m][nf][0] + bz.x, 0.f));
            cv.y = f2bu(fmaxf(acc[m][nf][1] + bz.y, 0.f));
            cv.z = f2bu(fmaxf(acc[m][nf][2] + bz.z, 0.f));
            cv.w = f2bu(fmaxf(acc[m][nf][3] + bz.w, 0.f));
            *(ushort4*)&convb[((size_t)bn2*PP + col)*64 + rbase] = cv;
        }
    }
}

// K4b: 3x3 avgpool on convb -> kbufb bf16 [bn][k][d], vbufT bf16 [bn][d][k]
__global__ __launch_bounds__(256) void k_pool(const __hip_bfloat16* __restrict__ convb,
        __hip_bfloat16* __restrict__ kbufb, __hip_bfloat16* __restrict__ vbufT) {
    int idx = blockIdx.x*256 + threadIdx.x;
    int dg = idx % 8; idx /= 8;
    int pp = idx % PK; idx /= PK;
    int bn2 = idx;
    int kv = bn2 & 1, bn = bn2 >> 1;
    int qy = pp / KHW, qx = pp % KHW;
    float s[8] = {0,0,0,0,0,0,0,0};
    const __hip_bfloat16* base = convb + (size_t)bn2*PP*64 + dg*8;
    #pragma unroll
    for (int sy = 0; sy < 3; ++sy)
        #pragma unroll
        for (int sx = 0; sx < 3; ++sx) {
            union { bf16x8 v; unsigned short h[8]; } c;
            c.v = *(const bf16x8*)(base + ((size_t)(qy*3+sy)*WW + qx*3+sx)*64);
            #pragma unroll
            for (int j = 0; j < 8; ++j) s[j] += bu2f(c.h[j]);
        }
    if (kv == 0) {
        union { ushort4 u[2]; unsigned short h[8]; } cv;
        #pragma unroll
        for (int j = 0; j < 8; ++j) cv.h[j] = f2bu(s[j] * (1.f/9.f));
        ushort4* dst = (ushort4*)(kbufb + ((size_t)bn*PK + pp)*64 + dg*8);
        dst[0] = cv.u[0]; dst[1] = cv.u[1];
    } else {
        #pragma unroll
        for (int j = 0; j < 8; ++j)
            vbufT[((size_t)bn*64 + dg*8 + j)*PK + pp] = __float2bfloat16(s[j]*(1.f/81.f));
    }
}

// K5: fused MFMA leave-one-out sigmoid attention + output MLP.
__global__ __launch_bounds__(256) void k_attn4(const __hip_bfloat16* __restrict__ qb16,
        const __hip_bfloat16* __restrict__ kbufb, const __hip_bfloat16* __restrict__ vbufT,
        const __hip_bfloat16* __restrict__ xvb16, const float* __restrict__ scales,
        const __hip_bfloat16* __restrict__ w1sw, const __hip_bfloat16* __restrict__ w2sw,
        const float* __restrict__ b1, const float* __restrict__ b2,
        float* __restrict__ out) {
    __shared__ __align__(16) char smem[40960];
    char* Qs  = smem;
    char* Ks  = smem + 8192;    // -> Rs
    char* Vs  = smem + 16384;   // -> W1s
    char* Ps  = smem + 24576;   // -> W2s
    char* XVs = smem + 32768;   // -> Ts
    int tid = threadIdx.x;
    int wid = tid >> 6, lane = tid & 63;
    int qt = blockIdx.x % 36;
    int bn = blockIdx.x / 36;
    int b = bn / NVIEW, n = bn % NVIEW;
    int p0 = qt*64;
    float sc = scales[n];

    {   // stage Q and XV (same [p][d] layout, pre-swizzled source)
        const char* gq  = (const char*)(qb16  + ((size_t)bn*PP + p0)*64);
        const char* gxv = (const char*)(xvb16 + ((size_t)bn*PP + p0)*64);
        #pragma unroll
        for (int i = 0; i < 2; ++i) {
            int s = wid*2 + i;
            int lin = s*1024 + lane*16;
            int r = lin >> 7, c = (lin >> 4) & 7;
            int gof = (r<<7) + ((c ^ (r&7)) << 4);
            load_lds16(gq + gof, Qs + s*1024);
            load_lds16(gxv + gof, XVs + s*1024);
        }
    }
    int arow = wid*16 + (lane&15);
    int brow = lane&15;
    int gcol = lane>>4;
    int vrow = tid >> 2;
    int vc2 = (tid & 3) * 2;

    f32x4 oacc[4];
    #pragma unroll
    for (int i = 0; i < 4; ++i) oacc[i] = (f32x4){0,0,0,0};

    for (int mi = 0; mi < NVIEW-1; ++mi) {
        int m = mi + (mi >= n ? 1 : 0);
        int bnk = b*NVIEW + m;
        const char* gk = (const char*)(kbufb + (size_t)bnk*PK*64);
        const __hip_bfloat16* gv = vbufT + (size_t)bnk*64*PK;
        for (int kc = 0; kc < 4; ++kc) {
            __syncthreads();
            #pragma unroll
            for (int i = 0; i < 2; ++i) {
                int s = wid*2 + i;
                int lin = s*1024 + lane*16;
                int r = lin >> 7, c = (lin >> 4) & 7;
                int gof = (r<<7) + ((c ^ (r&7)) << 4);
                load_lds16(gk + (size_t)kc*8192 + gof, Ks + s*1024);
            }
            {
                const __hip_bfloat16* src = gv + vrow*PK + kc*64 + vc2*8;
                bf16x8 v0 = *(const bf16x8*)src;
                bf16x8 v1 = *(const bf16x8*)(src+8);
                *(bf16x8*)(Vs + vrow*128 + ((vc2 ^ (vrow&7))<<4)) = v0;
                *(bf16x8*)(Vs + vrow*128 + (((vc2+1) ^ (vrow&7))<<4)) = v1;
            }
            __syncthreads();
            f32x4 sacc[4];
            #pragma unroll
            for (int i = 0; i < 4; ++i) sacc[i] = (f32x4){0,0,0,0};
            #pragma unroll
            for (int kk = 0; kk < 2; ++kk) {
                int g = kk*4 + gcol;
                bf16x8 af = *(const bf16x8*)(Ks + arow*128 + ((g ^ (arow&7))<<4));
                #pragma unroll
                for (int nf = 0; nf < 4; ++nf) {
                    int q = nf*16 + brow;
                    bf16x8 bq = *(const bf16x8*)(Qs + q*128 + ((g ^ (q&7))<<4));
                    sacc[nf] = __builtin_amdgcn_mfma_f32_16x16x32_bf16(af, bq, sacc[nf], 0,0,0);
                }
            }
            {
                int kbase = wid*16 + gcol*4;
                #pragma unroll
                for (int nf = 0; nf < 4; ++nf) {
                    int q = nf*16 + brow;
                    ushort4 pu;
                    float e0 = __expf(-sacc[nf][0]*0.125f);
                    float e1 = __expf(-sacc[nf][1]*0.125f);
                    float e2 = __expf(-sacc[nf][2]*0.125f);
                    float e3 = __expf(-sacc[nf][3]*0.125f);
                    pu.x = f2bu(__builtin_amdgcn_rcpf(1.f+e0));
                    pu.y = f2bu(__builtin_amdgcn_rcpf(1.f+e1));
                    pu.z = f2bu(__builtin_amdgcn_rcpf(1.f+e2));
                    pu.w = f2bu(__builtin_amdgcn_rcpf(1.f+e3));
                    *(ushort4*)(Ps + q*128 + (((kbase>>3) ^ (q&7))<<4) + (kbase&7)*2) = pu;
                }
            }
            __syncthreads();
            #pragma unroll
            for (int kk = 0; kk < 2; ++kk) {
                int g = kk*4 + gcol;
                int qr = wid*16 + brow;
                bf16x8 pf = *(const bf16x8*)(Ps + qr*128 + ((g ^ (qr&7))<<4));
                #pragma unroll
                for (int nf = 0; nf < 4; ++nf) {
                    int d = nf*16 + brow;
                    bf16x8 vf = *(const bf16x8*)(Vs + d*128 + ((g ^ (d&7))<<4));
                    oacc[nf] = __builtin_amdgcn_mfma_f32_16x16x32_bf16(pf, vf, oacc[nf], 0,0,0);
                }
            }
        }
    }

    // ---- fused epilogue ----
    __syncthreads();   // all attn LDS reads done; safe to repurpose Ks/Vs/Ps
    #pragma unroll
    for (int i = 0; i < 4; ++i) {
        int seg = wid*4 + i;
        const char* src = (seg < 8) ? (const char*)w1sw + seg*1024
                                    : (const char*)w2sw + (seg-8)*1024;
        load_lds16(src + lane*16, ((seg < 8) ? Vs : Ps) + (seg & 7)*1024);
    }
    #pragma unroll
    for (int nf = 0; nf < 4; ++nf) {
        int d = nf*16 + brow;
        #pragma unroll
        for (int r = 0; r < 4; ++r) {
            int q = wid*16 + gcol*4 + r;
            int off = q*128 + (((d>>3) ^ (q&7))<<4) + (d&7)*2;
            float xv = bu2f(*(const unsigned short*)(XVs + off));
            *(unsigned short*)(Ks + off) = f2bu(fmaxf(oacc[nf][r] + sc*xv, 0.f));
        }
    }
    __syncthreads();
    f32x4 acc1[4];
    #pragma unroll
    for (int nf = 0; nf < 4; ++nf) acc1[nf] = (f32x4){0,0,0,0};
    #pragma unroll
    for (int kk = 0; kk < 2; ++kk) {
        int g = kk*4 + gcol;
        int oc = wid*16 + brow;
        bf16x8 af = *(const bf16x8*)(Vs + oc*128 + ((g ^ (oc&7)) << 4));
        #pragma unroll
        for (int nf = 0; nf < 4; ++nf) {
            int px = nf*16 + brow;
            bf16x8 bf = *(const bf16x8*)(Ks + px*128 + ((g ^ (px&7)) << 4));
            acc1[nf] = __builtin_amdgcn_mfma_f32_16x16x32_bf16(af, bf, acc1[nf], 0,0,0);
        }
    }
    {
        int oc0 = wid*16 + gcol*4;
        float4 bz = *(const float4*)&b1[oc0];
        #pragma unroll
        for (int nf = 0; nf < 4; ++nf) {
            int px = nf*16 + brow;
            ushort4 tv;
            tv.x = f2bu(fmaxf(acc1[nf][0] + bz.x, 0.f));
            tv.y = f2bu(fmaxf(acc1[nf][1] + bz.y, 0.f));
            tv.z = f2bu(fmaxf(acc1[nf][2] + bz.z, 0.f));
            tv.w = f2bu(fmaxf(acc1[nf][3] + bz.w, 0.f));
            *(ushort4*)(XVs + px*128 + (((oc0>>3) ^ (px&7)) << 4) + (oc0&7)*2) = tv;
        }
    }
    __syncthreads();
    f32x4 acc2[4];
    #pragma unroll
    for (int nf = 0; nf < 4; ++nf) acc2[nf] = (f32x4){0,0,0,0};
    #pragma unroll
    for (int kk = 0; kk < 2; ++kk) {
        int g = kk*4 + gcol;
        int oc = wid*16 + brow;
        bf16x8 af = *(const bf16x8*)(Ps + oc*128 + ((g ^ (oc&7)) << 4));
        #pragma unroll
        for (int nf = 0; nf < 4; ++nf) {
            int px = nf*16 + brow;
            bf16x8 bf = *(const bf16x8*)(XVs + px*128 + ((g ^ (px&7)) << 4));
            acc2[nf] = __builtin_amdgcn_mfma_f32_16x16x32_bf16(af, bf, acc2[nf], 0,0,0);
        }
    }
    {
        int oc0 = wid*16 + gcol*4;
        float4 bz = *(const float4*)&b2[oc0];
        #pragma unroll
        for (int nf = 0; nf < 4; ++nf) {
            int px = nf*16 + brow;
            float* dst = out + ((size_t)bn*64 + oc0)*PP + p0 + px;
            dst[0*PP] = fmaxf(acc2[nf][0] + bz.x, 0.f);
            dst[1*PP] = fmaxf(acc2[nf][1] + bz.y, 0.f);
            dst[2*PP] = fmaxf(acc2[nf][2] + bz.z, 0.f);
            dst[3*PP] = fmaxf(acc2[nf][3] + bz.w, 0.f);
        }
    }
}

extern "C" void kernel_launch(void* const* d_in, const int* in_sizes, int n_in,
                              void* d_out, int out_size, void* d_ws, size_t ws_size,
                              hipStream_t stream) {
    (void)in_sizes; (void)n_in; (void)out_size; (void)ws_size;
    const float* x      = (const float*)d_in[0];
    const float* pa_w1  = (const float*)d_in[1];
    const float* pa_b1  = (const float*)d_in[2];
    const float* pa_w2  = (const float*)d_in[3];
    const float* pa_b2  = (const float*)d_in[4];
    const float* pa_w3  = (const float*)d_in[5];
    const float* pa_b3  = (const float*)d_in[6];
    const float* pa_cw1 = (const float*)d_in[7];
    const float* pa_cb1 = (const float*)d_in[8];
    const float* pa_cw2 = (const float*)d_in[9];
    const float* pa_cb2 = (const float*)d_in[10];
    const float* kv_w   = (const float*)d_in[11];
    const float* kv_b   = (const float*)d_in[12];
    const float* out_w1 = (const float*)d_in[13];
    const float* out_b1 = (const float*)d_in[14];
    const float* out_w2 = (const float*)d_in[15];
    const float* out_b2 = (const float*)d_in[16];
    const float* scales = (const float*)d_in[17];
    float* out = (float*)d_out;
    float* ws  = (float*)d_ws;

    __hip_bfloat16* weffb = (__hip_bfloat16*)(ws + OFF_WEFFB);
    float* beff = ws + OFF_BEFF;
    __hip_bfloat16* cw2b  = (__hip_bfloat16*)(ws + OFF_CW2B);
    __hip_bfloat16* wkvb  = (__hip_bfloat16*)(ws + OFF_WKVB);
    __hip_bfloat16* padxT = (__hip_bfloat16*)(ws + OFF_PADXT);
    __hip_bfloat16* qb16  = (__hip_bfloat16*)(ws + OFF_QB16);
    __hip_bfloat16* kbufb = (__hip_bfloat16*)(ws + OFF_KB16);
    __hip_bfloat16* vbufT = (__hip_bfloat16*)(ws + OFF_VB16T);
    __hip_bfloat16* kvpad = (__hip_bfloat16*)(ws + OFF_KVPAD);
    __hip_bfloat16* convb = (__hip_bfloat16*)(ws + OFF_CONVB);
    __hip_bfloat16* w1sw  = (__hip_bfloat16*)(ws + OFF_W1SW);
    __hip_bfloat16* w2sw  = (__hip_bfloat16*)(ws + OFF_W2SW);
    __hip_bfloat16* xvb16 = (__hip_bfloat16*)(ws + OFF_XVB16);

    k_prep<<<PREP_BLOCKS, 192, 0, stream>>>(pa_cw1, pa_cb1, pa_w1, pa_b1,
                                            pa_w2, pa_b2, pa_w3, pa_b3,
                                            kv_w, pa_cw2, out_w1, out_w2, x,
                                            weffb, beff, wkvb, cw2b,
                                            w1sw, w2sw, kvpad, padxT);
    k_mfc<<<NTOT/64, 256, 0, stream>>>(weffb, padxT, cw2b, beff, pa_cb2,
                                       xvb16, qb16, kvpad);
    k_kvgemm<<<BN*2*PP/128, 256, 0, stream>>>(wkvb, kvpad, kv_b, convb);
    k_pool<<<BN*2*PK*8/256, 256, 0, stream>>>(convb, kbufb, vbufT);
    k_attn4<<<BN*36, 256, 0, stream>>>(qb16, kbufb, vbufT, xvb16, scales,
                                       w1sw, w2sw, out_b1, out_b2, out);
}